// Round 1
// 392.911 us; speedup vs baseline: 2.0838x; 2.0838x over previous
//
#include <hip/hip_runtime.h>

#define NROWS 2048
#define SLEN  1024
#define FEAT  25088
#define DFC   512
#define DG1   512
#define DG2   256
#define CSPLIT 128   // k-splits for centers partial GEMM

typedef __attribute__((ext_vector_type(8))) short short8;
typedef __attribute__((ext_vector_type(4))) float f32x4;

__device__ __forceinline__ unsigned short bfbits(float f) {
  unsigned int u = __float_as_uint(f);
  u += 0x7fffu + ((u >> 16) & 1u);   // RNE to bf16
  return (unsigned short)(u >> 16);
}

// ---------- transpose fp32 [K][N] -> bf16 [N][K] ----------
__global__ void transpose_cvt_k(const float* __restrict__ src, unsigned short* __restrict__ dst,
                                int K, int Ncol) {
  __shared__ float tile[64][65];
  int kb = blockIdx.x * 64, nb = blockIdx.y * 64;
  int tx = threadIdx.x & 63, ty = threadIdx.x >> 6;
  #pragma unroll
  for (int i = ty; i < 64; i += 4)
    tile[i][tx] = src[(size_t)(kb + i) * Ncol + (nb + tx)];
  __syncthreads();
  #pragma unroll
  for (int i = ty; i < 64; i += 4)
    dst[(size_t)(nb + i) * K + (kb + tx)] = bfbits(tile[tx][i]);
}

// ---------- MFMA GEMM: C[M][N] (+=, atomic) = A[M][K] * BT[N][K]^T ----------
// 128x128 tile, 4 waves (2x2), each wave 64x64 via 4x4 frags of 16x16x32.
// AF32: A is fp32 (converted during staging); else A is bf16 (ushort).
template<bool AF32>
__global__ __launch_bounds__(256) void gemm_k(const void* __restrict__ Aptr,
    const unsigned short* __restrict__ BT, float* __restrict__ Cacc,
    int K, int Ncols, int tiles_n, int ksteps) {
  __shared__ unsigned short Al[128 * 40];  // stride 40 elems (80B) -> ~2-way banks
  __shared__ unsigned short Bl[128 * 40];  // B stored [n][k]
  int tid = threadIdx.x;
  int m0 = (blockIdx.x / tiles_n) * 128;
  int n0 = (blockIdx.x % tiles_n) * 128;
  int kbase = blockIdx.y * ksteps * 32;
  int wid = tid >> 6, lane = tid & 63;
  int wm = wid >> 1, wn = wid & 1;
  int lrow = lane & 15, lko = lane >> 4;

  f32x4 acc[4][4];
  #pragma unroll
  for (int i = 0; i < 4; i++)
    #pragma unroll
    for (int j = 0; j < 4; j++) acc[i][j] = (f32x4){0.f, 0.f, 0.f, 0.f};

  for (int t = 0; t < ksteps; ++t) {
    int k0 = kbase + t * 32;
    __syncthreads();
    if constexpr (AF32) {
      const float* A = (const float*)Aptr;
      #pragma unroll
      for (int i = 0; i < 4; i++) {
        int idx = tid + i * 256;          // 1024 float4 chunks: 128 rows x 8
        int row = idx >> 3, kq = idx & 7;
        float4 v = *reinterpret_cast<const float4*>(A + (size_t)(m0 + row) * K + k0 + kq * 4);
        ushort4 u;
        u.x = bfbits(v.x); u.y = bfbits(v.y); u.z = bfbits(v.z); u.w = bfbits(v.w);
        *reinterpret_cast<ushort4*>(&Al[row * 40 + kq * 4]) = u;
      }
    } else {
      const unsigned short* A = (const unsigned short*)Aptr;
      #pragma unroll
      for (int i = 0; i < 2; i++) {
        int idx = tid + i * 256;          // 512 16B chunks: 128 rows x 4
        int row = idx >> 2, kq = idx & 3;
        int4 v = *reinterpret_cast<const int4*>(A + (size_t)(m0 + row) * K + k0 + kq * 8);
        *reinterpret_cast<int4*>(&Al[row * 40 + kq * 8]) = v;
      }
    }
    #pragma unroll
    for (int i = 0; i < 2; i++) {
      int idx = tid + i * 256;
      int row = idx >> 2, kq = idx & 3;
      int4 v = *reinterpret_cast<const int4*>(BT + (size_t)(n0 + row) * K + k0 + kq * 8);
      *reinterpret_cast<int4*>(&Bl[row * 40 + kq * 8]) = v;
    }
    __syncthreads();
    short8 af[4], bfv[4];
    #pragma unroll
    for (int mi = 0; mi < 4; mi++)
      af[mi] = *reinterpret_cast<const short8*>(&Al[(wm * 64 + mi * 16 + lrow) * 40 + lko * 8]);
    #pragma unroll
    for (int ni = 0; ni < 4; ni++)
      bfv[ni] = *reinterpret_cast<const short8*>(&Bl[(wn * 64 + ni * 16 + lrow) * 40 + lko * 8]);
    #pragma unroll
    for (int mi = 0; mi < 4; mi++)
      #pragma unroll
      for (int ni = 0; ni < 4; ni++)
        acc[mi][ni] = __builtin_amdgcn_mfma_f32_16x16x32_bf16(af[mi], bfv[ni], acc[mi][ni], 0, 0, 0);
  }
  #pragma unroll
  for (int mi = 0; mi < 4; mi++)
    #pragma unroll
    for (int ni = 0; ni < 4; ni++)
      #pragma unroll
      for (int r = 0; r < 4; r++) {
        int row = m0 + wm * 64 + mi * 16 + lko * 4 + r;   // C/D: row=(lane>>4)*4+r
        int col = n0 + wn * 64 + ni * 16 + lrow;          //      col=lane&15
        atomicAdd(&Cacc[(size_t)row * Ncols + col], acc[mi][ni][r]);
      }
}

// ---------- feats finalize: +bias -> fp32 out + bf16 copy ----------
__global__ void feats_fin_k(const float* __restrict__ facc, const float* __restrict__ bfc,
                            float* __restrict__ outf, unsigned short* __restrict__ outbf) {
  int i = blockIdx.y;
  int n = blockIdx.x * 256 + threadIdx.x;
  float v = facc[(size_t)i * DFC + n] + bfc[n];
  outf[(size_t)i * DFC + n] = v;
  outbf[(size_t)i * DFC + n] = bfbits(v);
}

// ---------- exact label path ----------
// stage 1: per-128-row-chunk class partial sums of x, float4-vectorized.
// grid (ceil(FEAT/4/256)=25, 8); partials sxp[8][4][FEAT]
__global__ void seg_sum_part_k(const float* __restrict__ x, const int* __restrict__ slab,
                               float* __restrict__ sxp) {
  int k4 = blockIdx.x * 256 + threadIdx.x;
  if (k4 >= FEAT / 4) return;
  int k = k4 * 4;
  int i0 = blockIdx.y * 128, i1 = i0 + 128;
  float4 a0 = {0,0,0,0}, a1 = {0,0,0,0}, a2 = {0,0,0,0}, a3 = {0,0,0,0};
  #pragma unroll 4
  for (int i = i0; i < i1; i++) {
    float4 v = *reinterpret_cast<const float4*>(x + (size_t)i * FEAT + k);
    int c = slab[i];
    float m0 = (c == 0) ? 1.f : 0.f, m1 = (c == 1) ? 1.f : 0.f;
    float m2 = (c == 2) ? 1.f : 0.f, m3 = (c == 3) ? 1.f : 0.f;
    a0.x += m0 * v.x; a0.y += m0 * v.y; a0.z += m0 * v.z; a0.w += m0 * v.w;
    a1.x += m1 * v.x; a1.y += m1 * v.y; a1.z += m1 * v.z; a1.w += m1 * v.w;
    a2.x += m2 * v.x; a2.y += m2 * v.y; a2.z += m2 * v.z; a2.w += m2 * v.w;
    a3.x += m3 * v.x; a3.y += m3 * v.y; a3.z += m3 * v.z; a3.w += m3 * v.w;
  }
  size_t base = (size_t)blockIdx.y * 4 * FEAT;
  *reinterpret_cast<float4*>(sxp + base + 0 * FEAT + k) = a0;
  *reinterpret_cast<float4*>(sxp + base + 1 * FEAT + k) = a1;
  *reinterpret_cast<float4*>(sxp + base + 2 * FEAT + k) = a2;
  *reinterpret_cast<float4*>(sxp + base + 3 * FEAT + k) = a3;
}

// stage 2: deterministic double reduce of the 8 partials. grid (25, 4)
__global__ void seg_sum_reduce_k(const float* __restrict__ sxp, float* __restrict__ sx) {
  int k4 = blockIdx.x * 256 + threadIdx.x;
  if (k4 >= FEAT / 4) return;
  int k = k4 * 4;
  int c = blockIdx.y;
  double s0 = 0, s1 = 0, s2 = 0, s3 = 0;
  #pragma unroll
  for (int p = 0; p < 8; p++) {
    float4 v = *reinterpret_cast<const float4*>(sxp + ((size_t)p * 4 + c) * FEAT + k);
    s0 += (double)v.x; s1 += (double)v.y; s2 += (double)v.z; s3 += (double)v.w;
  }
  float4 r; r.x = (float)s0; r.y = (float)s1; r.z = (float)s2; r.w = (float)s3;
  *reinterpret_cast<float4*>(sx + (size_t)c * FEAT + k) = r;
}

__global__ void count_src_k(const int* __restrict__ slab, int* __restrict__ cnt) {
  __shared__ int c[4];
  if (threadIdx.x < 4) c[threadIdx.x] = 0;
  __syncthreads();
  for (int i = threadIdx.x; i < SLEN; i += 256) atomicAdd(&c[slab[i]], 1);
  __syncthreads();
  if (threadIdx.x < 4) cnt[threadIdx.x] = c[threadIdx.x];
}

// centers partial: grid (8 nblk, CSPLIT ksplit); block 256 = 4 classes x 64 cols
// double partials -> full parallelism without losing the exact-path precision
__global__ void centers_part_k(const float* __restrict__ sx, const float* __restrict__ W,
                               double* __restrict__ cpart) {
  int n = blockIdx.x * 64 + (threadIdx.x & 63);
  int cc = threadIdx.x >> 6;
  int kb = blockIdx.y * (FEAT / CSPLIT), ke = kb + FEAT / CSPLIT;  // 196 iters
  const float* sr = sx + (size_t)cc * FEAT;
  double acc = 0.0;
  #pragma unroll 4
  for (int k = kb; k < ke; k++)
    acc += (double)sr[k] * (double)W[(size_t)k * DFC + n];
  cpart[((size_t)blockIdx.y * 4 + cc) * DFC + n] = acc;
}

__global__ void centers_reduce_k(const double* __restrict__ cpart, const float* __restrict__ bfc,
                                 const int* __restrict__ cntsrc, float* __restrict__ Cent) {
  int idx = blockIdx.x * 256 + threadIdx.x;  // cc*512+n
  int cc = idx >> 9, n = idx & 511;
  double s = 0.0;
  #pragma unroll 4
  for (int p = 0; p < CSPLIT; p++) s += cpart[((size_t)p * 4 + cc) * DFC + n];
  Cent[idx] = (float)(s + (double)cntsrc[cc] * (double)bfc[n]);
}

// wc[k][j] = sum_n W[k][n] * Cent[j][n]  (float4 row loads)
__global__ void wc_k(const float* __restrict__ W, const float* __restrict__ Cent,
                     float* __restrict__ wc) {
  __shared__ float cs[4 * DFC];
  for (int i = threadIdx.x; i < 4 * DFC; i += 256) cs[i] = Cent[i];
  __syncthreads();
  int k = blockIdx.x * 256 + threadIdx.x;
  if (k >= FEAT) return;
  const float* wr = W + (size_t)k * DFC;
  double a0 = 0, a1 = 0, a2 = 0, a3 = 0;
  #pragma unroll 2
  for (int n = 0; n < DFC; n += 4) {
    float4 w4 = *reinterpret_cast<const float4*>(wr + n);
    a0 += (double)w4.x * cs[0 * DFC + n] + (double)w4.y * cs[0 * DFC + n + 1]
        + (double)w4.z * cs[0 * DFC + n + 2] + (double)w4.w * cs[0 * DFC + n + 3];
    a1 += (double)w4.x * cs[1 * DFC + n] + (double)w4.y * cs[1 * DFC + n + 1]
        + (double)w4.z * cs[1 * DFC + n + 2] + (double)w4.w * cs[1 * DFC + n + 3];
    a2 += (double)w4.x * cs[2 * DFC + n] + (double)w4.y * cs[2 * DFC + n + 1]
        + (double)w4.z * cs[2 * DFC + n + 2] + (double)w4.w * cs[2 * DFC + n + 3];
    a3 += (double)w4.x * cs[3 * DFC + n] + (double)w4.y * cs[3 * DFC + n + 1]
        + (double)w4.z * cs[3 * DFC + n + 2] + (double)w4.w * cs[3 * DFC + n + 3];
  }
  float4 r; r.x = (float)a0; r.y = (float)a1; r.z = (float)a2; r.w = (float)a3;
  *reinterpret_cast<float4*>(wc + 4 * (size_t)k) = r;
}

__global__ void kj_k(const float* __restrict__ Cent, const float* __restrict__ bfc,
                     float* __restrict__ Kj) {
  int j = threadIdx.x >> 6, lane = threadIdx.x & 63;
  float cn = 0.f, bc = 0.f;
  for (int n = lane; n < DFC; n += 64) {
    float c = Cent[j * DFC + n];
    cn += c * c; bc += bfc[n] * c;
  }
  #pragma unroll
  for (int m = 32; m >= 1; m >>= 1) { cn += __shfl_xor(cn, m); bc += __shfl_xor(bc, m); }
  if (lane == 0) Kj[j] = cn - 2.f * bc;
}

// one 256-thread BLOCK per target row: score_j = Kj[j] - 2 * x_t . wc_j ; argmin
__global__ void d2_labels_k(const float* __restrict__ x, const float* __restrict__ wc,
                            const float* __restrict__ Kj, int* __restrict__ tlab) {
  int row = blockIdx.x;
  int tid = threadIdx.x;
  const float* xr = x + (size_t)(SLEN + row) * FEAT;
  double a0 = 0, a1 = 0, a2 = 0, a3 = 0;
  #pragma unroll 2
  for (int k = tid; k < FEAT; k += 256) {
    float xv = xr[k];
    float4 w4 = *reinterpret_cast<const float4*>(wc + 4 * (size_t)k);
    a0 += (double)xv * w4.x; a1 += (double)xv * w4.y;
    a2 += (double)xv * w4.z; a3 += (double)xv * w4.w;
  }
  #pragma unroll
  for (int m = 32; m >= 1; m >>= 1) {
    a0 += __shfl_xor(a0, m); a1 += __shfl_xor(a1, m);
    a2 += __shfl_xor(a2, m); a3 += __shfl_xor(a3, m);
  }
  __shared__ double s[4][4];
  int wid = tid >> 6, lane = tid & 63;
  if (lane == 0) { s[wid][0] = a0; s[wid][1] = a1; s[wid][2] = a2; s[wid][3] = a3; }
  __syncthreads();
  if (tid == 0) {
    double t0 = s[0][0] + s[1][0] + s[2][0] + s[3][0];
    double t1 = s[0][1] + s[1][1] + s[2][1] + s[3][1];
    double t2 = s[0][2] + s[1][2] + s[2][2] + s[3][2];
    double t3 = s[0][3] + s[1][3] + s[2][3] + s[3][3];
    double s0 = (double)Kj[0] - 2.0 * t0;
    double s1 = (double)Kj[1] - 2.0 * t1;
    double s2 = (double)Kj[2] - 2.0 * t2;
    double s3 = (double)Kj[3] - 2.0 * t3;
    int bi = 0; double b = s0;
    if (s1 < b) { b = s1; bi = 1; }
    if (s2 < b) { b = s2; bi = 2; }
    if (s3 < b) { b = s3; bi = 3; }
    tlab[row] = bi;
  }
}

__global__ void finalize_labels_k(const int* __restrict__ slab, const int* __restrict__ tlab,
                                  const int* __restrict__ cntsrc, int* __restrict__ alllab,
                                  float* __restrict__ dinv) {
  __shared__ int ct[4];
  if (threadIdx.x < 4) ct[threadIdx.x] = 0;
  __syncthreads();
  for (int i = threadIdx.x; i < SLEN; i += 256) atomicAdd(&ct[tlab[i]], 1);
  __syncthreads();
  for (int i = threadIdx.x; i < NROWS; i += 256) {
    int lab = (i < SLEN) ? slab[i] : tlab[i - SLEN];
    alllab[i] = lab;
    float rs = (i < SLEN) ? (2.f + (float)ct[lab])
                          : (1.f + (float)cntsrc[lab] + (float)ct[lab]);
    dinv[i] = 1.f / sqrtf(rs);
  }
}

// ---------- A_norm dense write ----------
__global__ void anorm_k(const int* __restrict__ alllab, const float* __restrict__ dinv,
                        float* __restrict__ Aout) {
  int i = blockIdx.y;
  int j = blockIdx.x * 256 + threadIdx.x;
  int li = alllab[i], lj = alllab[j];
  float di = dinv[i], dj = dinv[j];
  float v;
  if (i == j) v = 2.f * di * dj;
  else if (i < SLEN && j < SLEN) v = 0.f;
  else v = (li == lj) ? di * dj : 0.f;
  Aout[(size_t)i * NROWS + j] = v;
}

// ---------- propagation: class sums of dinv_j * X_j ----------
__global__ void reduce_st_k(const float* __restrict__ Xacc, const int* __restrict__ alllab,
                            const float* __restrict__ dinv, float* __restrict__ ST, int D) {
  int n = blockIdx.x * 256 + threadIdx.x;
  int i0 = blockIdx.y * 32, i1 = i0 + 32;
  float s[4] = {0, 0, 0, 0}, tt[4] = {0, 0, 0, 0};
  for (int i = i0; i < i1; ++i) {
    float v = dinv[i] * Xacc[(size_t)i * D + n];
    int lab = alllab[i];
    bool src = i < SLEN;
    #pragma unroll
    for (int c = 0; c < 4; c++) {
      s[c]  += (src && lab == c) ? v : 0.f;
      tt[c] += (!src && lab == c) ? v : 0.f;
    }
  }
  #pragma unroll
  for (int c = 0; c < 4; c++) {
    atomicAdd(&ST[c * D + n], s[c]);
    atomicAdd(&ST[(4 + c) * D + n], tt[c]);
  }
}

// z_i = dinv*(2*dinv*X_i + T[l])            (i < S)
//     = dinv*(S[l] + T[l] + dinv*X_i)       (i >= S); out = relu(z + bias)
__global__ void apply_prop_k(const float* __restrict__ Xacc, const float* __restrict__ ST,
                             const int* __restrict__ alllab, const float* __restrict__ dinv,
                             const float* __restrict__ bias, float* __restrict__ outf,
                             unsigned short* __restrict__ outbf, int D) {
  int i = blockIdx.y;
  int n = blockIdx.x * 256 + threadIdx.x;
  float dv = dinv[i];
  int lab = alllab[i];
  float xv = Xacc[(size_t)i * D + n];
  float z;
  if (i < SLEN) z = dv * (2.f * dv * xv + ST[(4 + lab) * D + n]);
  else          z = dv * (ST[lab * D + n] + ST[(4 + lab) * D + n] + dv * xv);
  z += bias[n];
  z = fmaxf(z, 0.f);
  if (outf)  outf[(size_t)i * D + n] = z;
  if (outbf) outbf[(size_t)i * D + n] = bfbits(z);
}

extern "C" void kernel_launch(void* const* d_in, const int* in_sizes, int n_in,
                              void* d_out, int out_size, void* d_ws, size_t ws_size,
                              hipStream_t stream) {
  const float* x    = (const float*)d_in[0];
  const float* Wfc  = (const float*)d_in[1];
  const float* bfc  = (const float*)d_in[2];
  const float* Wg1  = (const float*)d_in[3];
  const float* bg1  = (const float*)d_in[4];
  const float* Wg2  = (const float*)d_in[5];
  const float* bg2  = (const float*)d_in[6];
  const int*   slab = (const int*)d_in[7];

  float* out = (float*)d_out;
  float* out_h = out;                       // 2048*256
  float* out_A = out + 524288;              // 2048*2048
  float* out_f = out + 4718592;             // 2048*512

  char* w = (char*)d_ws;
  unsigned short* wT   = (unsigned short*)(w);
  unsigned short* g1T  = (unsigned short*)(w + 25690112);
  unsigned short* g2T  = (unsigned short*)(w + 26214400);
  float* facc          = (float*)(w + 26476544);
  unsigned short* fbf  = (unsigned short*)(w + 30670848);
  float* x1acc         = (float*)(w + 32768000);
  unsigned short* h1bf = (unsigned short*)(w + 36962304);
  float* x2acc         = (float*)(w + 39059456);
  float* sx            = (float*)(w + 41156608);
  float* Cent          = (float*)(w + 41623552);
  float* wc            = (float*)(w + 41631744);
  float* Kj            = (float*)(w + 42033152);
  int*   tlab          = (int*)(w + 42033216);
  int*   alllab        = (int*)(w + 42037312);
  float* dinv          = (float*)(w + 42045504);
  int*   cntsrc        = (int*)(w + 42053696);
  float* ST1           = (float*)(w + 42053760);
  float* ST2           = (float*)(w + 42070144);

  // aliased scratch (regions dead during the label phase):
  float*  sxp     = (float*)(w + 26476544);   // alias facc  (needs 3.21 MB <= 4 MB)
  double* cpart_d = (double*)(w + 39059456);  // alias x2acc (needs 2 MB == 2 MB)

  // zero atomic accumulators (x2acc is zeroed later, after cpart_d is consumed)
  hipMemsetAsync(facc,  0, (size_t)NROWS * DFC * 4, stream);
  hipMemsetAsync(x1acc, 0, (size_t)NROWS * DG1 * 4, stream);
  hipMemsetAsync(ST1,   0, 8 * DG1 * 4, stream);
  hipMemsetAsync(ST2,   0, 8 * DG2 * 4, stream);

  // weight transposes + bf16 convert
  transpose_cvt_k<<<dim3(FEAT / 64, DFC / 64), 256, 0, stream>>>(Wfc, wT, FEAT, DFC);
  transpose_cvt_k<<<dim3(DFC / 64, DG1 / 64), 256, 0, stream>>>(Wg1, g1T, DFC, DG1);
  transpose_cvt_k<<<dim3(DG1 / 64, DG2 / 64), 256, 0, stream>>>(Wg2, g2T, DG1, DG2);

  // FC GEMM: 2048x25088 @ 25088x512, split-K 8 (784/8 = 98 BK-steps each)
  gemm_k<true><<<dim3(16 * 4, 8), 256, 0, stream>>>(x, wT, facc, FEAT, DFC, 4, 98);
  feats_fin_k<<<dim3(DFC / 256, NROWS), 256, 0, stream>>>(facc, bfc, out_f, fbf);

  // exact label path (fp32/f64 from x, independent of bf16 feats)
  // NOTE: sxp aliases facc -> must run after feats_fin_k (stream-ordered).
  seg_sum_part_k<<<dim3(25, 8), 256, 0, stream>>>(x, slab, sxp);
  seg_sum_reduce_k<<<dim3(25, 4), 256, 0, stream>>>(sxp, sx);
  count_src_k<<<1, 256, 0, stream>>>(slab, cntsrc);
  centers_part_k<<<dim3(DFC / 64, CSPLIT), 256, 0, stream>>>(sx, Wfc, cpart_d);
  centers_reduce_k<<<dim3(4 * DFC / 256), 256, 0, stream>>>(cpart_d, bfc, cntsrc, Cent);
  wc_k<<<dim3(FEAT / 256), 256, 0, stream>>>(Wfc, Cent, wc);
  kj_k<<<1, 256, 0, stream>>>(Cent, bfc, Kj);
  d2_labels_k<<<dim3(NROWS - SLEN), 256, 0, stream>>>(x, wc, Kj, tlab);
  finalize_labels_k<<<1, 256, 0, stream>>>(slab, tlab, cntsrc, alllab, dinv);

  // A_norm dense output
  anorm_k<<<dim3(NROWS / 256, NROWS), 256, 0, stream>>>(alllab, dinv, out_A);

  // GCN layer 1: X1 = feats_bf @ Wg1 ; propagate ; relu
  gemm_k<false><<<dim3(16 * 4, 4), 256, 0, stream>>>(fbf, g1T, x1acc, DFC, DG1, 4, 4);
  reduce_st_k<<<dim3(DG1 / 256, 64), 256, 0, stream>>>(x1acc, alllab, dinv, ST1, DG1);
  apply_prop_k<<<dim3(DG1 / 256, NROWS), 256, 0, stream>>>(x1acc, ST1, alllab, dinv, bg1,
                                                           nullptr, h1bf, DG1);

  // GCN layer 2: X2 = h1_bf @ Wg2 ; propagate ; relu -> out_h
  // x2acc zeroed here (its space held cpart_d during the label phase)
  hipMemsetAsync(x2acc, 0, (size_t)NROWS * DG2 * 4, stream);
  gemm_k<false><<<dim3(16 * 2, 8), 256, 0, stream>>>(h1bf, g2T, x2acc, DG1, DG2, 2, 2);
  reduce_st_k<<<dim3(DG2 / 256, 64), 256, 0, stream>>>(x2acc, alllab, dinv, ST2, DG2);
  apply_prop_k<<<dim3(DG2 / 256, NROWS), 256, 0, stream>>>(x2acc, ST2, alllab, dinv, bg2,
                                                           out_h, nullptr, DG2);

  (void)in_sizes; (void)n_in; (void)out_size; (void)ws_size;
}

// Round 2
// 381.485 us; speedup vs baseline: 2.1462x; 1.0300x over previous
//
#include <hip/hip_runtime.h>

#define NROWS 2048
#define SLEN  1024
#define FEAT  25088
#define DFC   512
#define DG1   512
#define DG2   256
#define CSPLIT 128   // k-splits for centers partial GEMM

typedef __attribute__((ext_vector_type(8))) short short8;
typedef __attribute__((ext_vector_type(4))) float f32x4;

__device__ __forceinline__ unsigned short bfbits(float f) {
  unsigned int u = __float_as_uint(f);
  u += 0x7fffu + ((u >> 16) & 1u);   // RNE to bf16
  return (unsigned short)(u >> 16);
}

// async global->LDS, 16B per lane; lds base must be wave-uniform (HW adds lane*16)
__device__ __forceinline__ void load_lds16(const void* g, void* l) {
  __builtin_amdgcn_global_load_lds(
      (const __attribute__((address_space(1))) unsigned int*)g,
      (__attribute__((address_space(3))) unsigned int*)l, 16, 0, 0);
}

// ---------- transpose fp32 [K][N] -> bf16 [N][K] ----------
__global__ void transpose_cvt_k(const float* __restrict__ src, unsigned short* __restrict__ dst,
                                int K, int Ncol) {
  __shared__ float tile[64][65];
  int kb = blockIdx.x * 64, nb = blockIdx.y * 64;
  int tx = threadIdx.x & 63, ty = threadIdx.x >> 6;
  #pragma unroll
  for (int i = ty; i < 64; i += 4)
    tile[i][tx] = src[(size_t)(kb + i) * Ncol + (nb + tx)];
  __syncthreads();
  #pragma unroll
  for (int i = ty; i < 64; i += 4)
    dst[(size_t)(nb + i) * K + (kb + tx)] = bfbits(tile[tx][i]);
}

// ---------- MFMA GEMM: C[M][N] (+=, atomic) = A[M][K] * BT[N][K]^T ----------
// 128x128 tile, BK=64, 4 waves (2x2), each wave 64x64 via 4x4 frags of 16x16x32.
// LDS: linear [128 rows][64 bf16] per operand, 16B-chunk XOR swizzle p = c ^ (r&7).
//   - B (and A when bf16) staged with global_load_lds w16: linear LDS dest,
//     inverse-swizzled GLOBAL source (rule: both-sides-or-neither).
//   - A fp32 path: reg-staged convert, ds_write to swizzled chunk.
//   - ds_read_b128 frag reads apply the same XOR -> uniform 8 lanes/slot, conflict-free.
template<bool AF32>
__global__ __launch_bounds__(256) void gemm_k(const void* __restrict__ Aptr,
    const unsigned short* __restrict__ BT, float* __restrict__ Cacc,
    int K, int Ncols, int tiles_n, int ksteps) {
  __shared__ unsigned short Al[128 * 64];  // 16 KB
  __shared__ unsigned short Bl[128 * 64];  // 16 KB
  int tid = threadIdx.x;
  int m0 = (blockIdx.x / tiles_n) * 128;
  int n0 = (blockIdx.x % tiles_n) * 128;
  int kbase = blockIdx.y * ksteps * 64;
  int wid = tid >> 6, lane = tid & 63;
  int wm = wid >> 1, wn = wid & 1;
  int lrow = lane & 15, lko = lane >> 4;

  f32x4 acc[4][4];
  #pragma unroll
  for (int i = 0; i < 4; i++)
    #pragma unroll
    for (int j = 0; j < 4; j++) acc[i][j] = (f32x4){0.f, 0.f, 0.f, 0.f};

  for (int t = 0; t < ksteps; ++t) {
    int k0 = kbase + t * 64;
    __syncthreads();   // previous step's frags consumed before overwrite
    if constexpr (AF32) {
      const float* A = (const float*)Aptr;
      #pragma unroll
      for (int j = 0; j < 4; j++) {
        int ch = tid + j * 256;            // logical chunk: r = ch>>3, c = ch&7
        int r = ch >> 3, c = ch & 7;
        const float* g = A + (size_t)(m0 + r) * K + k0 + c * 8;
        float4 v0 = *reinterpret_cast<const float4*>(g);
        float4 v1 = *reinterpret_cast<const float4*>(g + 4);
        unsigned int w0 = (unsigned)bfbits(v0.x) | ((unsigned)bfbits(v0.y) << 16);
        unsigned int w1 = (unsigned)bfbits(v0.z) | ((unsigned)bfbits(v0.w) << 16);
        unsigned int w2 = (unsigned)bfbits(v1.x) | ((unsigned)bfbits(v1.y) << 16);
        unsigned int w3 = (unsigned)bfbits(v1.z) | ((unsigned)bfbits(v1.w) << 16);
        int p = c ^ (r & 7);
        int4 o; o.x = (int)w0; o.y = (int)w1; o.z = (int)w2; o.w = (int)w3;
        *reinterpret_cast<int4*>((char*)Al + r * 128 + p * 16) = o;
      }
    } else {
      const unsigned short* A = (const unsigned short*)Aptr;
      #pragma unroll
      for (int j = 0; j < 4; j++) {
        int chb = j * 256 + wid * 64;      // wave-uniform physical base chunk
        int ch = chb + lane;               // physical chunk: r = ch>>3, p = ch&7
        int r = ch >> 3, c = (ch & 7) ^ (r & 7);
        load_lds16(A + (size_t)(m0 + r) * K + k0 + c * 8, (char*)Al + chb * 16);
      }
    }
    #pragma unroll
    for (int j = 0; j < 4; j++) {
      int chb = j * 256 + wid * 64;
      int ch = chb + lane;
      int r = ch >> 3, c = (ch & 7) ^ (r & 7);
      load_lds16(BT + (size_t)(n0 + r) * K + k0 + c * 8, (char*)Bl + chb * 16);
    }
    __syncthreads();   // drains vmcnt (global_load_lds) + lgkmcnt (ds_write)
    #pragma unroll
    for (int kk = 0; kk < 2; kk++) {
      short8 af[4], bfv[4];
      #pragma unroll
      for (int mi = 0; mi < 4; mi++) {
        int R = wm * 64 + mi * 16 + lrow;
        int slot = ((kk << 2) | lko) ^ (lrow & 7);
        af[mi] = *reinterpret_cast<const short8*>((char*)Al + R * 128 + slot * 16);
      }
      #pragma unroll
      for (int ni = 0; ni < 4; ni++) {
        int R = wn * 64 + ni * 16 + lrow;
        int slot = ((kk << 2) | lko) ^ (lrow & 7);
        bfv[ni] = *reinterpret_cast<const short8*>((char*)Bl + R * 128 + slot * 16);
      }
      #pragma unroll
      for (int mi = 0; mi < 4; mi++)
        #pragma unroll
        for (int ni = 0; ni < 4; ni++)
          acc[mi][ni] = __builtin_amdgcn_mfma_f32_16x16x32_bf16(af[mi], bfv[ni], acc[mi][ni], 0, 0, 0);
    }
  }
  #pragma unroll
  for (int mi = 0; mi < 4; mi++)
    #pragma unroll
    for (int ni = 0; ni < 4; ni++)
      #pragma unroll
      for (int r = 0; r < 4; r++) {
        int row = m0 + wm * 64 + mi * 16 + lko * 4 + r;   // C/D: row=(lane>>4)*4+r
        int col = n0 + wn * 64 + ni * 16 + lrow;          //      col=lane&15
        atomicAdd(&Cacc[(size_t)row * Ncols + col], acc[mi][ni][r]);
      }
}

// ---------- feats finalize: +bias -> fp32 out + bf16 copy ----------
__global__ void feats_fin_k(const float* __restrict__ facc, const float* __restrict__ bfc,
                            float* __restrict__ outf, unsigned short* __restrict__ outbf) {
  int i = blockIdx.y;
  int n = blockIdx.x * 256 + threadIdx.x;
  float v = facc[(size_t)i * DFC + n] + bfc[n];
  outf[(size_t)i * DFC + n] = v;
  outbf[(size_t)i * DFC + n] = bfbits(v);
}

// ---------- exact label path ----------
// stage 1: per-64-row-chunk class partial sums of x, float4-vectorized.
// grid (25, 16); partials sxp[16][4][FEAT]
__global__ void seg_sum_part_k(const float* __restrict__ x, const int* __restrict__ slab,
                               float* __restrict__ sxp) {
  int k4 = blockIdx.x * 256 + threadIdx.x;
  if (k4 >= FEAT / 4) return;
  int k = k4 * 4;
  int i0 = blockIdx.y * 64, i1 = i0 + 64;
  float4 a0 = {0,0,0,0}, a1 = {0,0,0,0}, a2 = {0,0,0,0}, a3 = {0,0,0,0};
  #pragma unroll 4
  for (int i = i0; i < i1; i++) {
    float4 v = *reinterpret_cast<const float4*>(x + (size_t)i * FEAT + k);
    int c = slab[i];
    float m0 = (c == 0) ? 1.f : 0.f, m1 = (c == 1) ? 1.f : 0.f;
    float m2 = (c == 2) ? 1.f : 0.f, m3 = (c == 3) ? 1.f : 0.f;
    a0.x += m0 * v.x; a0.y += m0 * v.y; a0.z += m0 * v.z; a0.w += m0 * v.w;
    a1.x += m1 * v.x; a1.y += m1 * v.y; a1.z += m1 * v.z; a1.w += m1 * v.w;
    a2.x += m2 * v.x; a2.y += m2 * v.y; a2.z += m2 * v.z; a2.w += m2 * v.w;
    a3.x += m3 * v.x; a3.y += m3 * v.y; a3.z += m3 * v.z; a3.w += m3 * v.w;
  }
  size_t base = (size_t)blockIdx.y * 4 * FEAT;
  *reinterpret_cast<float4*>(sxp + base + 0 * FEAT + k) = a0;
  *reinterpret_cast<float4*>(sxp + base + 1 * FEAT + k) = a1;
  *reinterpret_cast<float4*>(sxp + base + 2 * FEAT + k) = a2;
  *reinterpret_cast<float4*>(sxp + base + 3 * FEAT + k) = a3;
}

// stage 2: deterministic double reduce of the 16 partials. grid (25, 4)
__global__ void seg_sum_reduce_k(const float* __restrict__ sxp, float* __restrict__ sx) {
  int k4 = blockIdx.x * 256 + threadIdx.x;
  if (k4 >= FEAT / 4) return;
  int k = k4 * 4;
  int c = blockIdx.y;
  double s0 = 0, s1 = 0, s2 = 0, s3 = 0;
  #pragma unroll
  for (int p = 0; p < 16; p++) {
    float4 v = *reinterpret_cast<const float4*>(sxp + ((size_t)p * 4 + c) * FEAT + k);
    s0 += (double)v.x; s1 += (double)v.y; s2 += (double)v.z; s3 += (double)v.w;
  }
  float4 r; r.x = (float)s0; r.y = (float)s1; r.z = (float)s2; r.w = (float)s3;
  *reinterpret_cast<float4*>(sx + (size_t)c * FEAT + k) = r;
}

__global__ void count_src_k(const int* __restrict__ slab, int* __restrict__ cnt) {
  __shared__ int c[4];
  if (threadIdx.x < 4) c[threadIdx.x] = 0;
  __syncthreads();
  for (int i = threadIdx.x; i < SLEN; i += 256) atomicAdd(&c[slab[i]], 1);
  __syncthreads();
  if (threadIdx.x < 4) cnt[threadIdx.x] = c[threadIdx.x];
}

// centers partial: grid (8 nblk, CSPLIT ksplit); block 256 = 4 classes x 64 cols
__global__ void centers_part_k(const float* __restrict__ sx, const float* __restrict__ W,
                               double* __restrict__ cpart) {
  int n = blockIdx.x * 64 + (threadIdx.x & 63);
  int cc = threadIdx.x >> 6;
  int kb = blockIdx.y * (FEAT / CSPLIT), ke = kb + FEAT / CSPLIT;  // 196 iters
  const float* sr = sx + (size_t)cc * FEAT;
  double acc = 0.0;
  #pragma unroll 4
  for (int k = kb; k < ke; k++)
    acc += (double)sr[k] * (double)W[(size_t)k * DFC + n];
  cpart[((size_t)blockIdx.y * 4 + cc) * DFC + n] = acc;
}

__global__ void centers_reduce_k(const double* __restrict__ cpart, const float* __restrict__ bfc,
                                 const int* __restrict__ cntsrc, float* __restrict__ Cent) {
  int idx = blockIdx.x * 256 + threadIdx.x;  // cc*512+n
  int cc = idx >> 9, n = idx & 511;
  double s = 0.0;
  #pragma unroll 4
  for (int p = 0; p < CSPLIT; p++) s += cpart[((size_t)p * 4 + cc) * DFC + n];
  Cent[idx] = (float)(s + (double)cntsrc[cc] * (double)bfc[n]);
}

// wc[k][j] = sum_n W[k][n] * Cent[j][n]  (float4 row loads)
__global__ void wc_k(const float* __restrict__ W, const float* __restrict__ Cent,
                     float* __restrict__ wc) {
  __shared__ float cs[4 * DFC];
  for (int i = threadIdx.x; i < 4 * DFC; i += 256) cs[i] = Cent[i];
  __syncthreads();
  int k = blockIdx.x * 256 + threadIdx.x;
  if (k >= FEAT) return;
  const float* wr = W + (size_t)k * DFC;
  double a0 = 0, a1 = 0, a2 = 0, a3 = 0;
  #pragma unroll 2
  for (int n = 0; n < DFC; n += 4) {
    float4 w4 = *reinterpret_cast<const float4*>(wr + n);
    a0 += (double)w4.x * cs[0 * DFC + n] + (double)w4.y * cs[0 * DFC + n + 1]
        + (double)w4.z * cs[0 * DFC + n + 2] + (double)w4.w * cs[0 * DFC + n + 3];
    a1 += (double)w4.x * cs[1 * DFC + n] + (double)w4.y * cs[1 * DFC + n + 1]
        + (double)w4.z * cs[1 * DFC + n + 2] + (double)w4.w * cs[1 * DFC + n + 3];
    a2 += (double)w4.x * cs[2 * DFC + n] + (double)w4.y * cs[2 * DFC + n + 1]
        + (double)w4.z * cs[2 * DFC + n + 2] + (double)w4.w * cs[2 * DFC + n + 3];
    a3 += (double)w4.x * cs[3 * DFC + n] + (double)w4.y * cs[3 * DFC + n + 1]
        + (double)w4.z * cs[3 * DFC + n + 2] + (double)w4.w * cs[3 * DFC + n + 3];
  }
  float4 r; r.x = (float)a0; r.y = (float)a1; r.z = (float)a2; r.w = (float)a3;
  *reinterpret_cast<float4*>(wc + 4 * (size_t)k) = r;
}

__global__ void kj_k(const float* __restrict__ Cent, const float* __restrict__ bfc,
                     float* __restrict__ Kj) {
  int j = threadIdx.x >> 6, lane = threadIdx.x & 63;
  float cn = 0.f, bc = 0.f;
  for (int n = lane; n < DFC; n += 64) {
    float c = Cent[j * DFC + n];
    cn += c * c; bc += bfc[n] * c;
  }
  #pragma unroll
  for (int m = 32; m >= 1; m >>= 1) { cn += __shfl_xor(cn, m); bc += __shfl_xor(bc, m); }
  if (lane == 0) Kj[j] = cn - 2.f * bc;
}

// one 256-thread BLOCK per target row: score_j = Kj[j] - 2 * x_t . wc_j ; argmin
__global__ void d2_labels_k(const float* __restrict__ x, const float* __restrict__ wc,
                            const float* __restrict__ Kj, int* __restrict__ tlab) {
  int row = blockIdx.x;
  int tid = threadIdx.x;
  const float* xr = x + (size_t)(SLEN + row) * FEAT;
  double a0 = 0, a1 = 0, a2 = 0, a3 = 0;
  #pragma unroll 2
  for (int k = tid; k < FEAT; k += 256) {
    float xv = xr[k];
    float4 w4 = *reinterpret_cast<const float4*>(wc + 4 * (size_t)k);
    a0 += (double)xv * w4.x; a1 += (double)xv * w4.y;
    a2 += (double)xv * w4.z; a3 += (double)xv * w4.w;
  }
  #pragma unroll
  for (int m = 32; m >= 1; m >>= 1) {
    a0 += __shfl_xor(a0, m); a1 += __shfl_xor(a1, m);
    a2 += __shfl_xor(a2, m); a3 += __shfl_xor(a3, m);
  }
  __shared__ double s[4][4];
  int wid = tid >> 6, lane = tid & 63;
  if (lane == 0) { s[wid][0] = a0; s[wid][1] = a1; s[wid][2] = a2; s[wid][3] = a3; }
  __syncthreads();
  if (tid == 0) {
    double t0 = s[0][0] + s[1][0] + s[2][0] + s[3][0];
    double t1 = s[0][1] + s[1][1] + s[2][1] + s[3][1];
    double t2 = s[0][2] + s[1][2] + s[2][2] + s[3][2];
    double t3 = s[0][3] + s[1][3] + s[2][3] + s[3][3];
    double s0 = (double)Kj[0] - 2.0 * t0;
    double s1 = (double)Kj[1] - 2.0 * t1;
    double s2 = (double)Kj[2] - 2.0 * t2;
    double s3 = (double)Kj[3] - 2.0 * t3;
    int bi = 0; double b = s0;
    if (s1 < b) { b = s1; bi = 1; }
    if (s2 < b) { b = s2; bi = 2; }
    if (s3 < b) { b = s3; bi = 3; }
    tlab[row] = bi;
  }
}

__global__ void finalize_labels_k(const int* __restrict__ slab, const int* __restrict__ tlab,
                                  const int* __restrict__ cntsrc, int* __restrict__ alllab,
                                  float* __restrict__ dinv) {
  __shared__ int ct[4];
  if (threadIdx.x < 4) ct[threadIdx.x] = 0;
  __syncthreads();
  for (int i = threadIdx.x; i < SLEN; i += 256) atomicAdd(&ct[tlab[i]], 1);
  __syncthreads();
  for (int i = threadIdx.x; i < NROWS; i += 256) {
    int lab = (i < SLEN) ? slab[i] : tlab[i - SLEN];
    alllab[i] = lab;
    float rs = (i < SLEN) ? (2.f + (float)ct[lab])
                          : (1.f + (float)cntsrc[lab] + (float)ct[lab]);
    dinv[i] = 1.f / sqrtf(rs);
  }
}

// ---------- A_norm dense write (float4) ----------
__global__ void anorm_k(const int* __restrict__ alllab, const float* __restrict__ dinv,
                        float* __restrict__ Aout) {
  int i = blockIdx.y;
  int j0 = (blockIdx.x * 256 + threadIdx.x) * 4;
  int li = alllab[i];
  float di = dinv[i];
  int4 lj = *reinterpret_cast<const int4*>(alllab + j0);
  float4 dj = *reinterpret_cast<const float4*>(dinv + j0);
  int jj[4] = {lj.x, lj.y, lj.z, lj.w};
  float dd[4] = {dj.x, dj.y, dj.z, dj.w};
  float4 o;
  float* op = &o.x;
  #pragma unroll
  for (int e = 0; e < 4; e++) {
    int j = j0 + e;
    float v;
    if (i == j) v = 2.f * di * dd[e];
    else if (i < SLEN && j < SLEN) v = 0.f;
    else v = (li == jj[e]) ? di * dd[e] : 0.f;
    op[e] = v;
  }
  *reinterpret_cast<float4*>(Aout + (size_t)i * NROWS + j0) = o;
}

// ---------- propagation: class sums of dinv_j * X_j ----------
__global__ void reduce_st_k(const float* __restrict__ Xacc, const int* __restrict__ alllab,
                            const float* __restrict__ dinv, float* __restrict__ ST, int D) {
  int n = blockIdx.x * 256 + threadIdx.x;
  int i0 = blockIdx.y * 32, i1 = i0 + 32;
  float s[4] = {0, 0, 0, 0}, tt[4] = {0, 0, 0, 0};
  for (int i = i0; i < i1; ++i) {
    float v = dinv[i] * Xacc[(size_t)i * D + n];
    int lab = alllab[i];
    bool src = i < SLEN;
    #pragma unroll
    for (int c = 0; c < 4; c++) {
      s[c]  += (src && lab == c) ? v : 0.f;
      tt[c] += (!src && lab == c) ? v : 0.f;
    }
  }
  #pragma unroll
  for (int c = 0; c < 4; c++) {
    atomicAdd(&ST[c * D + n], s[c]);
    atomicAdd(&ST[(4 + c) * D + n], tt[c]);
  }
}

// z_i = dinv*(2*dinv*X_i + T[l])            (i < S)
//     = dinv*(S[l] + T[l] + dinv*X_i)       (i >= S); out = relu(z + bias)
__global__ void apply_prop_k(const float* __restrict__ Xacc, const float* __restrict__ ST,
                             const int* __restrict__ alllab, const float* __restrict__ dinv,
                             const float* __restrict__ bias, float* __restrict__ outf,
                             unsigned short* __restrict__ outbf, int D) {
  int i = blockIdx.y;
  int n = blockIdx.x * 256 + threadIdx.x;
  float dv = dinv[i];
  int lab = alllab[i];
  float xv = Xacc[(size_t)i * D + n];
  float z;
  if (i < SLEN) z = dv * (2.f * dv * xv + ST[(4 + lab) * D + n]);
  else          z = dv * (ST[lab * D + n] + ST[(4 + lab) * D + n] + dv * xv);
  z += bias[n];
  z = fmaxf(z, 0.f);
  if (outf)  outf[(size_t)i * D + n] = z;
  if (outbf) outbf[(size_t)i * D + n] = bfbits(z);
}

extern "C" void kernel_launch(void* const* d_in, const int* in_sizes, int n_in,
                              void* d_out, int out_size, void* d_ws, size_t ws_size,
                              hipStream_t stream) {
  const float* x    = (const float*)d_in[0];
  const float* Wfc  = (const float*)d_in[1];
  const float* bfc  = (const float*)d_in[2];
  const float* Wg1  = (const float*)d_in[3];
  const float* bg1  = (const float*)d_in[4];
  const float* Wg2  = (const float*)d_in[5];
  const float* bg2  = (const float*)d_in[6];
  const int*   slab = (const int*)d_in[7];

  float* out = (float*)d_out;
  float* out_h = out;                       // 2048*256
  float* out_A = out + 524288;              // 2048*2048
  float* out_f = out + 4718592;             // 2048*512

  char* w = (char*)d_ws;
  unsigned short* wT   = (unsigned short*)(w);
  unsigned short* g1T  = (unsigned short*)(w + 25690112);
  unsigned short* g2T  = (unsigned short*)(w + 26214400);
  float* facc          = (float*)(w + 26476544);
  unsigned short* fbf  = (unsigned short*)(w + 30670848);
  float* x1acc         = (float*)(w + 32768000);
  unsigned short* h1bf = (unsigned short*)(w + 36962304);
  float* x2acc         = (float*)(w + 39059456);
  float* sx            = (float*)(w + 41156608);
  float* Cent          = (float*)(w + 41623552);
  float* wc            = (float*)(w + 41631744);
  float* Kj            = (float*)(w + 42033152);
  int*   tlab          = (int*)(w + 42033216);
  int*   alllab        = (int*)(w + 42037312);
  float* dinv          = (float*)(w + 42045504);
  int*   cntsrc        = (int*)(w + 42053696);
  float* ST1           = (float*)(w + 42053760);
  float* ST2           = (float*)(w + 42070144);

  // aliased scratch (regions dead during the label phase):
  //   sxp: 16*4*FEAT*4 = 6.42 MB over x1acc/h1bf (consumed before centers_part writes cpart)
  //   cpart_d: 2 MB over x2acc (consumed before layer-2 GEMM; x2acc memset'd later)
  float*  sxp     = (float*)(w + 32768000);   // alias x1acc (+h1bf head)
  double* cpart_d = (double*)(w + 39059456);  // alias x2acc

  // zero atomic accumulators (x1acc/x2acc zeroed later — their space is label-phase scratch)
  hipMemsetAsync(facc,  0, (size_t)NROWS * DFC * 4, stream);
  hipMemsetAsync(ST1,   0, 8 * DG1 * 4, stream);
  hipMemsetAsync(ST2,   0, 8 * DG2 * 4, stream);

  // weight transposes + bf16 convert
  transpose_cvt_k<<<dim3(FEAT / 64, DFC / 64), 256, 0, stream>>>(Wfc, wT, FEAT, DFC);
  transpose_cvt_k<<<dim3(DFC / 64, DG1 / 64), 256, 0, stream>>>(Wg1, g1T, DFC, DG1);
  transpose_cvt_k<<<dim3(DG1 / 64, DG2 / 64), 256, 0, stream>>>(Wg2, g2T, DG1, DG2);

  // FC GEMM: 2048x25088 @ 25088x512, BK=64, split-K 8 (392/8 = 49 steps each)
  gemm_k<true><<<dim3(16 * 4, 8), 256, 0, stream>>>(x, wT, facc, FEAT, DFC, 4, 49);
  feats_fin_k<<<dim3(DFC / 256, NROWS), 256, 0, stream>>>(facc, bfc, out_f, fbf);

  // exact label path (fp32/f64 from x, independent of bf16 feats)
  seg_sum_part_k<<<dim3(25, 16), 256, 0, stream>>>(x, slab, sxp);
  seg_sum_reduce_k<<<dim3(25, 4), 256, 0, stream>>>(sxp, sx);
  count_src_k<<<1, 256, 0, stream>>>(slab, cntsrc);
  centers_part_k<<<dim3(DFC / 64, CSPLIT), 256, 0, stream>>>(sx, Wfc, cpart_d);
  centers_reduce_k<<<dim3(4 * DFC / 256), 256, 0, stream>>>(cpart_d, bfc, cntsrc, Cent);
  wc_k<<<dim3(FEAT / 256), 256, 0, stream>>>(Wfc, Cent, wc);
  kj_k<<<1, 256, 0, stream>>>(Cent, bfc, Kj);
  d2_labels_k<<<dim3(NROWS - SLEN), 256, 0, stream>>>(x, wc, Kj, tlab);
  finalize_labels_k<<<1, 256, 0, stream>>>(slab, tlab, cntsrc, alllab, dinv);

  // A_norm dense output
  anorm_k<<<dim3(NROWS / 1024, NROWS), 256, 0, stream>>>(alllab, dinv, out_A);

  // GCN layer 1: X1 = feats_bf @ Wg1 ; propagate ; relu
  // (x1acc zeroed here — its space held sxp during the label phase)
  hipMemsetAsync(x1acc, 0, (size_t)NROWS * DG1 * 4, stream);
  gemm_k<false><<<dim3(16 * 4, 4), 256, 0, stream>>>(fbf, g1T, x1acc, DFC, DG1, 4, 2);
  reduce_st_k<<<dim3(DG1 / 256, 64), 256, 0, stream>>>(x1acc, alllab, dinv, ST1, DG1);
  apply_prop_k<<<dim3(DG1 / 256, NROWS), 256, 0, stream>>>(x1acc, ST1, alllab, dinv, bg1,
                                                           nullptr, h1bf, DG1);

  // GCN layer 2: X2 = h1_bf @ Wg2 ; propagate ; relu -> out_h
  // (x2acc zeroed here — its space held cpart_d during the label phase)
  hipMemsetAsync(x2acc, 0, (size_t)NROWS * DG2 * 4, stream);
  gemm_k<false><<<dim3(16 * 2, 8), 256, 0, stream>>>(h1bf, g2T, x2acc, DG1, DG2, 2, 1);
  reduce_st_k<<<dim3(DG2 / 256, 64), 256, 0, stream>>>(x2acc, alllab, dinv, ST2, DG2);
  apply_prop_k<<<dim3(DG2 / 256, NROWS), 256, 0, stream>>>(x2acc, ST2, alllab, dinv, bg2,
                                                           out_h, nullptr, DG2);

  (void)in_sizes; (void)n_in; (void)out_size; (void)ws_size;
}

// Round 3
// 373.822 us; speedup vs baseline: 2.1902x; 1.0205x over previous
//
#include <hip/hip_runtime.h>

#define NROWS 2048
#define SLEN  1024
#define FEAT  25088
#define DFC   512
#define DG1   512
#define DG2   256
#define CSPLIT 128   // k-splits for centers partial GEMM

typedef __attribute__((ext_vector_type(8))) short short8;
typedef __attribute__((ext_vector_type(4))) float f32x4;

__device__ __forceinline__ unsigned short bfbits(float f) {
  unsigned int u = __float_as_uint(f);
  u += 0x7fffu + ((u >> 16) & 1u);   // RNE to bf16
  return (unsigned short)(u >> 16);
}

// HW packed f32->bf16 (RNE), 2 elems / instruction
__device__ __forceinline__ unsigned int cvtpk(float lo, float hi) {
  unsigned int r;
  asm("v_cvt_pk_bf16_f32 %0, %1, %2" : "=v"(r) : "v"(lo), "v"(hi));
  return r;
}

// async global->LDS, 16B per lane; lds base must be wave-uniform (HW adds lane*16)
__device__ __forceinline__ void load_lds16(const void* g, void* l) {
  __builtin_amdgcn_global_load_lds(
      (const __attribute__((address_space(1))) unsigned int*)g,
      (__attribute__((address_space(3))) unsigned int*)l, 16, 0, 0);
}

// ---------- transpose fp32 [K][N] -> bf16 [N][K] ----------
__global__ void transpose_cvt_k(const float* __restrict__ src, unsigned short* __restrict__ dst,
                                int K, int Ncol) {
  __shared__ float tile[64][65];
  int kb = blockIdx.x * 64, nb = blockIdx.y * 64;
  int tx = threadIdx.x & 63, ty = threadIdx.x >> 6;
  #pragma unroll
  for (int i = ty; i < 64; i += 4)
    tile[i][tx] = src[(size_t)(kb + i) * Ncol + (nb + tx)];
  __syncthreads();
  #pragma unroll
  for (int i = ty; i < 64; i += 4)
    dst[(size_t)(nb + i) * K + (kb + tx)] = bfbits(tile[tx][i]);
}

// ---------- MFMA GEMM: C[M][N] (+=, atomic) = A[M][K] * BT[N][K]^T ----------
// 128x128 tile, BK=64, 4 waves (2x2), each wave 64x64 via 4x4 frags of 16x16x32.
// Double-buffered LDS, ONE barrier per K-step:
//   issue next-tile loads (B via global_load_lds, A via reg loads) BEFORE the
//   current tile's ds_read+MFMA; convert+ds_write A AFTER MFMA; single barrier.
// LDS layout: linear [128 rows][64 bf16], 16B-chunk XOR swizzle p = c ^ (r&7)
// (inverse-swizzled global source for gload_lds; same XOR on ds_read).
template<bool AF32>
__global__ __launch_bounds__(256) void gemm_k(const void* __restrict__ Aptr,
    const unsigned short* __restrict__ BT, float* __restrict__ Cacc,
    int K, int Ncols, int tiles_n, int ksteps) {
  __shared__ unsigned short Al[2][128 * 64];  // 2 x 16 KB
  __shared__ unsigned short Bl[2][128 * 64];  // 2 x 16 KB
  int tid = threadIdx.x;
  int m0 = (blockIdx.x / tiles_n) * 128;
  int n0 = (blockIdx.x % tiles_n) * 128;
  int kbase = blockIdx.y * ksteps * 64;
  int wid = tid >> 6, lane = tid & 63;
  int wm = wid >> 1, wn = wid & 1;
  int lrow = lane & 15, lko = lane >> 4;

  f32x4 acc[4][4];
  #pragma unroll
  for (int i = 0; i < 4; i++)
    #pragma unroll
    for (int j = 0; j < 4; j++) acc[i][j] = (f32x4){0.f, 0.f, 0.f, 0.f};

  // A fp32 prefetch registers (4 chunks x 2 float4)
  float4 pa[8];

  // --- staging helpers ---
  auto loadA_regs = [&](int k0) {               // AF32: issue 8 dwordx4 to regs
    const float* A = (const float*)Aptr;
    #pragma unroll
    for (int j = 0; j < 4; j++) {
      int ch = tid + j * 256;                   // logical chunk: r=ch>>3, c=ch&7
      int r = ch >> 3, c = ch & 7;
      const float* g = A + (size_t)(m0 + r) * K + k0 + c * 8;
      pa[2 * j]     = *reinterpret_cast<const float4*>(g);
      pa[2 * j + 1] = *reinterpret_cast<const float4*>(g + 4);
    }
  };
  auto cvtWriteA = [&](int buf) {               // AF32: convert + swizzled ds_write
    #pragma unroll
    for (int j = 0; j < 4; j++) {
      int ch = tid + j * 256;
      int r = ch >> 3, c = ch & 7;
      int p = c ^ (r & 7);
      int4 o;
      o.x = (int)cvtpk(pa[2 * j].x,     pa[2 * j].y);
      o.y = (int)cvtpk(pa[2 * j].z,     pa[2 * j].w);
      o.z = (int)cvtpk(pa[2 * j + 1].x, pa[2 * j + 1].y);
      o.w = (int)cvtpk(pa[2 * j + 1].z, pa[2 * j + 1].w);
      *reinterpret_cast<int4*>((char*)Al[buf] + r * 128 + p * 16) = o;
    }
  };
  auto stageA_lds = [&](int buf, int k0) {      // bf16: direct global->LDS
    const unsigned short* A = (const unsigned short*)Aptr;
    #pragma unroll
    for (int j = 0; j < 4; j++) {
      int chb = j * 256 + wid * 64;             // wave-uniform physical base chunk
      int ch = chb + lane;
      int r = ch >> 3, c = (ch & 7) ^ (r & 7);  // inverse-swizzled global col
      load_lds16(A + (size_t)(m0 + r) * K + k0 + c * 8, (char*)Al[buf] + chb * 16);
    }
  };
  auto stageB = [&](int buf, int k0) {
    #pragma unroll
    for (int j = 0; j < 4; j++) {
      int chb = j * 256 + wid * 64;
      int ch = chb + lane;
      int r = ch >> 3, c = (ch & 7) ^ (r & 7);
      load_lds16(BT + (size_t)(n0 + r) * K + k0 + c * 8, (char*)Bl[buf] + chb * 16);
    }
  };

  // --- prologue: stage tile 0 into buf 0 ---
  if constexpr (AF32) { loadA_regs(kbase); cvtWriteA(0); }
  else                { stageA_lds(0, kbase); }
  stageB(0, kbase);
  __syncthreads();

  int cur = 0;
  for (int t = 0; t < ksteps; ++t) {
    int k1 = kbase + (t + 1) * 64;
    bool more = (t + 1 < ksteps);
    // issue next-tile loads early: they fly during ds_read + MFMA below
    if (more) {
      if constexpr (AF32) loadA_regs(k1);
      else                stageA_lds(cur ^ 1, k1);
      stageB(cur ^ 1, k1);
    }
    // compute current buffer
    #pragma unroll
    for (int kk = 0; kk < 2; kk++) {
      short8 af[4], bfv[4];
      #pragma unroll
      for (int mi = 0; mi < 4; mi++) {
        int R = wm * 64 + mi * 16 + lrow;
        int slot = ((kk << 2) | lko) ^ (lrow & 7);
        af[mi] = *reinterpret_cast<const short8*>((char*)Al[cur] + R * 128 + slot * 16);
      }
      #pragma unroll
      for (int ni = 0; ni < 4; ni++) {
        int R = wn * 64 + ni * 16 + lrow;
        int slot = ((kk << 2) | lko) ^ (lrow & 7);
        bfv[ni] = *reinterpret_cast<const short8*>((char*)Bl[cur] + R * 128 + slot * 16);
      }
      #pragma unroll
      for (int mi = 0; mi < 4; mi++)
        #pragma unroll
        for (int ni = 0; ni < 4; ni++)
          acc[mi][ni] = __builtin_amdgcn_mfma_f32_16x16x32_bf16(af[mi], bfv[ni], acc[mi][ni], 0, 0, 0);
    }
    // convert + write next A after MFMA (vmcnt wait lands here, post-compute)
    if constexpr (AF32) { if (more) cvtWriteA(cur ^ 1); }
    __syncthreads();   // drains gload_lds (vmcnt) + ds_writes (lgkm) for buf^1
    cur ^= 1;
  }

  #pragma unroll
  for (int mi = 0; mi < 4; mi++)
    #pragma unroll
    for (int ni = 0; ni < 4; ni++)
      #pragma unroll
      for (int r = 0; r < 4; r++) {
        int row = m0 + wm * 64 + mi * 16 + lko * 4 + r;   // C/D: row=(lane>>4)*4+r
        int col = n0 + wn * 64 + ni * 16 + lrow;          //      col=lane&15
        atomicAdd(&Cacc[(size_t)row * Ncols + col], acc[mi][ni][r]);
      }
}

// ---------- feats finalize: +bias -> fp32 out + bf16 copy ----------
__global__ void feats_fin_k(const float* __restrict__ facc, const float* __restrict__ bfc,
                            float* __restrict__ outf, unsigned short* __restrict__ outbf) {
  int i = blockIdx.y;
  int n = blockIdx.x * 256 + threadIdx.x;
  float v = facc[(size_t)i * DFC + n] + bfc[n];
  outf[(size_t)i * DFC + n] = v;
  outbf[(size_t)i * DFC + n] = bfbits(v);
}

// ---------- exact label path ----------
// stage 1: per-64-row-chunk class partial sums of x, float4-vectorized.
// grid (25, 16); partials sxp[16][4][FEAT]
__global__ void seg_sum_part_k(const float* __restrict__ x, const int* __restrict__ slab,
                               float* __restrict__ sxp) {
  int k4 = blockIdx.x * 256 + threadIdx.x;
  if (k4 >= FEAT / 4) return;
  int k = k4 * 4;
  int i0 = blockIdx.y * 64, i1 = i0 + 64;
  float4 a0 = {0,0,0,0}, a1 = {0,0,0,0}, a2 = {0,0,0,0}, a3 = {0,0,0,0};
  #pragma unroll 4
  for (int i = i0; i < i1; i++) {
    float4 v = *reinterpret_cast<const float4*>(x + (size_t)i * FEAT + k);
    int c = slab[i];
    float m0 = (c == 0) ? 1.f : 0.f, m1 = (c == 1) ? 1.f : 0.f;
    float m2 = (c == 2) ? 1.f : 0.f, m3 = (c == 3) ? 1.f : 0.f;
    a0.x += m0 * v.x; a0.y += m0 * v.y; a0.z += m0 * v.z; a0.w += m0 * v.w;
    a1.x += m1 * v.x; a1.y += m1 * v.y; a1.z += m1 * v.z; a1.w += m1 * v.w;
    a2.x += m2 * v.x; a2.y += m2 * v.y; a2.z += m2 * v.z; a2.w += m2 * v.w;
    a3.x += m3 * v.x; a3.y += m3 * v.y; a3.z += m3 * v.z; a3.w += m3 * v.w;
  }
  size_t base = (size_t)blockIdx.y * 4 * FEAT;
  *reinterpret_cast<float4*>(sxp + base + 0 * FEAT + k) = a0;
  *reinterpret_cast<float4*>(sxp + base + 1 * FEAT + k) = a1;
  *reinterpret_cast<float4*>(sxp + base + 2 * FEAT + k) = a2;
  *reinterpret_cast<float4*>(sxp + base + 3 * FEAT + k) = a3;
}

// stage 2: deterministic double reduce of the 16 partials. grid (25, 4)
__global__ void seg_sum_reduce_k(const float* __restrict__ sxp, float* __restrict__ sx) {
  int k4 = blockIdx.x * 256 + threadIdx.x;
  if (k4 >= FEAT / 4) return;
  int k = k4 * 4;
  int c = blockIdx.y;
  double s0 = 0, s1 = 0, s2 = 0, s3 = 0;
  #pragma unroll
  for (int p = 0; p < 16; p++) {
    float4 v = *reinterpret_cast<const float4*>(sxp + ((size_t)p * 4 + c) * FEAT + k);
    s0 += (double)v.x; s1 += (double)v.y; s2 += (double)v.z; s3 += (double)v.w;
  }
  float4 r; r.x = (float)s0; r.y = (float)s1; r.z = (float)s2; r.w = (float)s3;
  *reinterpret_cast<float4*>(sx + (size_t)c * FEAT + k) = r;
}

__global__ void count_src_k(const int* __restrict__ slab, int* __restrict__ cnt) {
  __shared__ int c[4];
  if (threadIdx.x < 4) c[threadIdx.x] = 0;
  __syncthreads();
  for (int i = threadIdx.x; i < SLEN; i += 256) atomicAdd(&c[slab[i]], 1);
  __syncthreads();
  if (threadIdx.x < 4) cnt[threadIdx.x] = c[threadIdx.x];
}

// centers partial: grid (8 nblk, CSPLIT ksplit); block 256 = 4 classes x 64 cols
__global__ void centers_part_k(const float* __restrict__ sx, const float* __restrict__ W,
                               double* __restrict__ cpart) {
  int n = blockIdx.x * 64 + (threadIdx.x & 63);
  int cc = threadIdx.x >> 6;
  int kb = blockIdx.y * (FEAT / CSPLIT), ke = kb + FEAT / CSPLIT;  // 196 iters
  const float* sr = sx + (size_t)cc * FEAT;
  double acc = 0.0;
  #pragma unroll 4
  for (int k = kb; k < ke; k++)
    acc += (double)sr[k] * (double)W[(size_t)k * DFC + n];
  cpart[((size_t)blockIdx.y * 4 + cc) * DFC + n] = acc;
}

__global__ void centers_reduce_k(const double* __restrict__ cpart, const float* __restrict__ bfc,
                                 const int* __restrict__ cntsrc, float* __restrict__ Cent) {
  int idx = blockIdx.x * 256 + threadIdx.x;  // cc*512+n
  int cc = idx >> 9, n = idx & 511;
  double s = 0.0;
  #pragma unroll 4
  for (int p = 0; p < CSPLIT; p++) s += cpart[((size_t)p * 4 + cc) * DFC + n];
  Cent[idx] = (float)(s + (double)cntsrc[cc] * (double)bfc[n]);
}

// wc[k][j] = sum_n W[k][n] * Cent[j][n]  (float4 row loads)
__global__ void wc_k(const float* __restrict__ W, const float* __restrict__ Cent,
                     float* __restrict__ wc) {
  __shared__ float cs[4 * DFC];
  for (int i = threadIdx.x; i < 4 * DFC; i += 256) cs[i] = Cent[i];
  __syncthreads();
  int k = blockIdx.x * 256 + threadIdx.x;
  if (k >= FEAT) return;
  const float* wr = W + (size_t)k * DFC;
  double a0 = 0, a1 = 0, a2 = 0, a3 = 0;
  #pragma unroll 2
  for (int n = 0; n < DFC; n += 4) {
    float4 w4 = *reinterpret_cast<const float4*>(wr + n);
    a0 += (double)w4.x * cs[0 * DFC + n] + (double)w4.y * cs[0 * DFC + n + 1]
        + (double)w4.z * cs[0 * DFC + n + 2] + (double)w4.w * cs[0 * DFC + n + 3];
    a1 += (double)w4.x * cs[1 * DFC + n] + (double)w4.y * cs[1 * DFC + n + 1]
        + (double)w4.z * cs[1 * DFC + n + 2] + (double)w4.w * cs[1 * DFC + n + 3];
    a2 += (double)w4.x * cs[2 * DFC + n] + (double)w4.y * cs[2 * DFC + n + 1]
        + (double)w4.z * cs[2 * DFC + n + 2] + (double)w4.w * cs[2 * DFC + n + 3];
    a3 += (double)w4.x * cs[3 * DFC + n] + (double)w4.y * cs[3 * DFC + n + 1]
        + (double)w4.z * cs[3 * DFC + n + 2] + (double)w4.w * cs[3 * DFC + n + 3];
  }
  float4 r; r.x = (float)a0; r.y = (float)a1; r.z = (float)a2; r.w = (float)a3;
  *reinterpret_cast<float4*>(wc + 4 * (size_t)k) = r;
}

__global__ void kj_k(const float* __restrict__ Cent, const float* __restrict__ bfc,
                     float* __restrict__ Kj) {
  int j = threadIdx.x >> 6, lane = threadIdx.x & 63;
  float cn = 0.f, bc = 0.f;
  for (int n = lane; n < DFC; n += 64) {
    float c = Cent[j * DFC + n];
    cn += c * c; bc += bfc[n] * c;
  }
  #pragma unroll
  for (int m = 32; m >= 1; m >>= 1) { cn += __shfl_xor(cn, m); bc += __shfl_xor(bc, m); }
  if (lane == 0) Kj[j] = cn - 2.f * bc;
}

// one 256-thread BLOCK per target row: score_j = Kj[j] - 2 * x_t . wc_j ; argmin
__global__ void d2_labels_k(const float* __restrict__ x, const float* __restrict__ wc,
                            const float* __restrict__ Kj, int* __restrict__ tlab) {
  int row = blockIdx.x;
  int tid = threadIdx.x;
  const float* xr = x + (size_t)(SLEN + row) * FEAT;
  double a0 = 0, a1 = 0, a2 = 0, a3 = 0;
  #pragma unroll 2
  for (int k = tid; k < FEAT; k += 256) {
    float xv = xr[k];
    float4 w4 = *reinterpret_cast<const float4*>(wc + 4 * (size_t)k);
    a0 += (double)xv * w4.x; a1 += (double)xv * w4.y;
    a2 += (double)xv * w4.z; a3 += (double)xv * w4.w;
  }
  #pragma unroll
  for (int m = 32; m >= 1; m >>= 1) {
    a0 += __shfl_xor(a0, m); a1 += __shfl_xor(a1, m);
    a2 += __shfl_xor(a2, m); a3 += __shfl_xor(a3, m);
  }
  __shared__ double s[4][4];
  int wid = tid >> 6, lane = tid & 63;
  if (lane == 0) { s[wid][0] = a0; s[wid][1] = a1; s[wid][2] = a2; s[wid][3] = a3; }
  __syncthreads();
  if (tid == 0) {
    double t0 = s[0][0] + s[1][0] + s[2][0] + s[3][0];
    double t1 = s[0][1] + s[1][1] + s[2][1] + s[3][1];
    double t2 = s[0][2] + s[1][2] + s[2][2] + s[3][2];
    double t3 = s[0][3] + s[1][3] + s[2][3] + s[3][3];
    double s0 = (double)Kj[0] - 2.0 * t0;
    double s1 = (double)Kj[1] - 2.0 * t1;
    double s2 = (double)Kj[2] - 2.0 * t2;
    double s3 = (double)Kj[3] - 2.0 * t3;
    int bi = 0; double b = s0;
    if (s1 < b) { b = s1; bi = 1; }
    if (s2 < b) { b = s2; bi = 2; }
    if (s3 < b) { b = s3; bi = 3; }
    tlab[row] = bi;
  }
}

__global__ void finalize_labels_k(const int* __restrict__ slab, const int* __restrict__ tlab,
                                  const int* __restrict__ cntsrc, int* __restrict__ alllab,
                                  float* __restrict__ dinv) {
  __shared__ int ct[4];
  if (threadIdx.x < 4) ct[threadIdx.x] = 0;
  __syncthreads();
  for (int i = threadIdx.x; i < SLEN; i += 256) atomicAdd(&ct[tlab[i]], 1);
  __syncthreads();
  for (int i = threadIdx.x; i < NROWS; i += 256) {
    int lab = (i < SLEN) ? slab[i] : tlab[i - SLEN];
    alllab[i] = lab;
    float rs = (i < SLEN) ? (2.f + (float)ct[lab])
                          : (1.f + (float)cntsrc[lab] + (float)ct[lab]);
    dinv[i] = 1.f / sqrtf(rs);
  }
}

// ---------- A_norm dense write (float4) ----------
__global__ void anorm_k(const int* __restrict__ alllab, const float* __restrict__ dinv,
                        float* __restrict__ Aout) {
  int i = blockIdx.y;
  int j0 = (blockIdx.x * 256 + threadIdx.x) * 4;
  int li = alllab[i];
  float di = dinv[i];
  int4 lj = *reinterpret_cast<const int4*>(alllab + j0);
  float4 dj = *reinterpret_cast<const float4*>(dinv + j0);
  int jj[4] = {lj.x, lj.y, lj.z, lj.w};
  float dd[4] = {dj.x, dj.y, dj.z, dj.w};
  float4 o;
  float* op = &o.x;
  #pragma unroll
  for (int e = 0; e < 4; e++) {
    int j = j0 + e;
    float v;
    if (i == j) v = 2.f * di * dd[e];
    else if (i < SLEN && j < SLEN) v = 0.f;
    else v = (li == jj[e]) ? di * dd[e] : 0.f;
    op[e] = v;
  }
  *reinterpret_cast<float4*>(Aout + (size_t)i * NROWS + j0) = o;
}

// ---------- propagation: class sums of dinv_j * X_j ----------
__global__ void reduce_st_k(const float* __restrict__ Xacc, const int* __restrict__ alllab,
                            const float* __restrict__ dinv, float* __restrict__ ST, int D) {
  int n = blockIdx.x * 256 + threadIdx.x;
  int i0 = blockIdx.y * 32, i1 = i0 + 32;
  float s[4] = {0, 0, 0, 0}, tt[4] = {0, 0, 0, 0};
  for (int i = i0; i < i1; ++i) {
    float v = dinv[i] * Xacc[(size_t)i * D + n];
    int lab = alllab[i];
    bool src = i < SLEN;
    #pragma unroll
    for (int c = 0; c < 4; c++) {
      s[c]  += (src && lab == c) ? v : 0.f;
      tt[c] += (!src && lab == c) ? v : 0.f;
    }
  }
  #pragma unroll
  for (int c = 0; c < 4; c++) {
    atomicAdd(&ST[c * D + n], s[c]);
    atomicAdd(&ST[(4 + c) * D + n], tt[c]);
  }
}

// z_i = dinv*(2*dinv*X_i + T[l])            (i < S)
//     = dinv*(S[l] + T[l] + dinv*X_i)       (i >= S); out = relu(z + bias)
__global__ void apply_prop_k(const float* __restrict__ Xacc, const float* __restrict__ ST,
                             const int* __restrict__ alllab, const float* __restrict__ dinv,
                             const float* __restrict__ bias, float* __restrict__ outf,
                             unsigned short* __restrict__ outbf, int D) {
  int i = blockIdx.y;
  int n = blockIdx.x * 256 + threadIdx.x;
  float dv = dinv[i];
  int lab = alllab[i];
  float xv = Xacc[(size_t)i * D + n];
  float z;
  if (i < SLEN) z = dv * (2.f * dv * xv + ST[(4 + lab) * D + n]);
  else          z = dv * (ST[lab * D + n] + ST[(4 + lab) * D + n] + dv * xv);
  z += bias[n];
  z = fmaxf(z, 0.f);
  if (outf)  outf[(size_t)i * D + n] = z;
  if (outbf) outbf[(size_t)i * D + n] = bfbits(z);
}

extern "C" void kernel_launch(void* const* d_in, const int* in_sizes, int n_in,
                              void* d_out, int out_size, void* d_ws, size_t ws_size,
                              hipStream_t stream) {
  const float* x    = (const float*)d_in[0];
  const float* Wfc  = (const float*)d_in[1];
  const float* bfc  = (const float*)d_in[2];
  const float* Wg1  = (const float*)d_in[3];
  const float* bg1  = (const float*)d_in[4];
  const float* Wg2  = (const float*)d_in[5];
  const float* bg2  = (const float*)d_in[6];
  const int*   slab = (const int*)d_in[7];

  float* out = (float*)d_out;
  float* out_h = out;                       // 2048*256
  float* out_A = out + 524288;              // 2048*2048
  float* out_f = out + 4718592;             // 2048*512

  char* w = (char*)d_ws;
  unsigned short* wT   = (unsigned short*)(w);
  unsigned short* g1T  = (unsigned short*)(w + 25690112);
  unsigned short* g2T  = (unsigned short*)(w + 26214400);
  float* facc          = (float*)(w + 26476544);
  unsigned short* fbf  = (unsigned short*)(w + 30670848);
  float* x1acc         = (float*)(w + 32768000);
  unsigned short* h1bf = (unsigned short*)(w + 36962304);
  float* x2acc         = (float*)(w + 39059456);
  float* sx            = (float*)(w + 41156608);
  float* Cent          = (float*)(w + 41623552);
  float* wc            = (float*)(w + 41631744);
  float* Kj            = (float*)(w + 42033152);
  int*   tlab          = (int*)(w + 42033216);
  int*   alllab        = (int*)(w + 42037312);
  float* dinv          = (float*)(w + 42045504);
  int*   cntsrc        = (int*)(w + 42053696);
  float* ST1           = (float*)(w + 42053760);
  float* ST2           = (float*)(w + 42070144);

  // aliased scratch (regions dead during the label phase):
  //   sxp: 16*4*FEAT*4 = 6.42 MB over x1acc/h1bf (consumed before layer-1 GEMM)
  //   cpart_d: 2 MB over x2acc (consumed before layer-2 GEMM; x2acc memset'd later)
  float*  sxp     = (float*)(w + 32768000);   // alias x1acc (+h1bf head)
  double* cpart_d = (double*)(w + 39059456);  // alias x2acc

  // zero atomic accumulators (x1acc/x2acc zeroed later — their space is label-phase scratch)
  hipMemsetAsync(facc,  0, (size_t)NROWS * DFC * 4, stream);
  hipMemsetAsync(ST1,   0, 8 * DG1 * 4, stream);
  hipMemsetAsync(ST2,   0, 8 * DG2 * 4, stream);

  // weight transposes + bf16 convert
  transpose_cvt_k<<<dim3(FEAT / 64, DFC / 64), 256, 0, stream>>>(Wfc, wT, FEAT, DFC);
  transpose_cvt_k<<<dim3(DFC / 64, DG1 / 64), 256, 0, stream>>>(Wg1, g1T, DFC, DG1);
  transpose_cvt_k<<<dim3(DG1 / 64, DG2 / 64), 256, 0, stream>>>(Wg2, g2T, DG1, DG2);

  // FC GEMM: 2048x25088 @ 25088x512, BK=64, split-K 8 (392/8 = 49 steps each)
  gemm_k<true><<<dim3(16 * 4, 8), 256, 0, stream>>>(x, wT, facc, FEAT, DFC, 4, 49);
  feats_fin_k<<<dim3(DFC / 256, NROWS), 256, 0, stream>>>(facc, bfc, out_f, fbf);

  // exact label path (fp32/f64 from x, independent of bf16 feats)
  seg_sum_part_k<<<dim3(25, 16), 256, 0, stream>>>(x, slab, sxp);
  seg_sum_reduce_k<<<dim3(25, 4), 256, 0, stream>>>(sxp, sx);
  count_src_k<<<1, 256, 0, stream>>>(slab, cntsrc);
  centers_part_k<<<dim3(DFC / 64, CSPLIT), 256, 0, stream>>>(sx, Wfc, cpart_d);
  centers_reduce_k<<<dim3(4 * DFC / 256), 256, 0, stream>>>(cpart_d, bfc, cntsrc, Cent);
  wc_k<<<dim3(FEAT / 256), 256, 0, stream>>>(Wfc, Cent, wc);
  kj_k<<<1, 256, 0, stream>>>(Cent, bfc, Kj);
  d2_labels_k<<<dim3(NROWS - SLEN), 256, 0, stream>>>(x, wc, Kj, tlab);
  finalize_labels_k<<<1, 256, 0, stream>>>(slab, tlab, cntsrc, alllab, dinv);

  // A_norm dense output
  anorm_k<<<dim3(NROWS / 1024, NROWS), 256, 0, stream>>>(alllab, dinv, out_A);

  // GCN layer 1: X1 = feats_bf @ Wg1 ; propagate ; relu
  // (x1acc zeroed here — its space held sxp during the label phase)
  hipMemsetAsync(x1acc, 0, (size_t)NROWS * DG1 * 4, stream);
  gemm_k<false><<<dim3(16 * 4, 4), 256, 0, stream>>>(fbf, g1T, x1acc, DFC, DG1, 4, 2);
  reduce_st_k<<<dim3(DG1 / 256, 64), 256, 0, stream>>>(x1acc, alllab, dinv, ST1, DG1);
  apply_prop_k<<<dim3(DG1 / 256, NROWS), 256, 0, stream>>>(x1acc, ST1, alllab, dinv, bg1,
                                                           nullptr, h1bf, DG1);

  // GCN layer 2: X2 = h1_bf @ Wg2 ; propagate ; relu -> out_h
  // (x2acc zeroed here — its space held cpart_d during the label phase)
  hipMemsetAsync(x2acc, 0, (size_t)NROWS * DG2 * 4, stream);
  gemm_k<false><<<dim3(16 * 2, 8), 256, 0, stream>>>(h1bf, g2T, x2acc, DG1, DG2, 2, 1);
  reduce_st_k<<<dim3(DG2 / 256, 64), 256, 0, stream>>>(x2acc, alllab, dinv, ST2, DG2);
  apply_prop_k<<<dim3(DG2 / 256, NROWS), 256, 0, stream>>>(x2acc, ST2, alllab, dinv, bg2,
                                                           out_h, nullptr, DG2);

  (void)in_sizes; (void)n_in; (void)out_size; (void)ws_size;
}

// Round 4
// 356.723 us; speedup vs baseline: 2.2952x; 1.0479x over previous
//
#include <hip/hip_runtime.h>

#define NROWS 2048
#define SLEN  1024
#define FEAT  25088
#define DFC   512
#define DG1   512
#define DG2   256
#define CSPLIT 128   // k-splits for centers partial GEMM

typedef __attribute__((ext_vector_type(8))) short short8;
typedef __attribute__((ext_vector_type(4))) float f32x4;

__device__ __forceinline__ unsigned short bfbits(float f) {
  unsigned int u = __float_as_uint(f);
  u += 0x7fffu + ((u >> 16) & 1u);   // RNE to bf16
  return (unsigned short)(u >> 16);
}

// HW packed f32->bf16 (RNE), 2 elems / instruction
__device__ __forceinline__ unsigned int cvtpk(float lo, float hi) {
  unsigned int r;
  asm("v_cvt_pk_bf16_f32 %0, %1, %2" : "=v"(r) : "v"(lo), "v"(hi));
  return r;
}

// async global->LDS, 16B per lane; lds base must be wave-uniform (HW adds lane*16)
__device__ __forceinline__ void load_lds16(const void* g, void* l) {
  __builtin_amdgcn_global_load_lds(
      (const __attribute__((address_space(1))) unsigned int*)g,
      (__attribute__((address_space(3))) unsigned int*)l, 16, 0, 0);
}

// ---------- transpose fp32 [K][N] -> bf16 [N][K] ----------
__global__ void transpose_cvt_k(const float* __restrict__ src, unsigned short* __restrict__ dst,
                                int K, int Ncol) {
  __shared__ float tile[64][65];
  int kb = blockIdx.x * 64, nb = blockIdx.y * 64;
  int tx = threadIdx.x & 63, ty = threadIdx.x >> 6;
  #pragma unroll
  for (int i = ty; i < 64; i += 4)
    tile[i][tx] = src[(size_t)(kb + i) * Ncol + (nb + tx)];
  __syncthreads();
  #pragma unroll
  for (int i = ty; i < 64; i += 4)
    dst[(size_t)(nb + i) * K + (kb + tx)] = bfbits(tile[tx][i]);
}

// ---------- FC MFMA GEMM: 256x256 tile, BK=32, 512 thr (8 waves 4x2) ----------
// A fp32 [M][K]; BT bf16 [N][K]; C += atomics (split-K over blockIdx.y).
// Pipeline (depth-2, ONE raw barrier/step, counted vmcnt — never 0 in loop):
//   step t: cvt+ds_write A(t+1) | ds_read frags(t) | issue A-regs(t+2)
//           lgkmcnt(0); s_barrier; | gload_lds B(t+2) into cur | MFMA | vmcnt(6)
// LDS [256][32] bf16 per buf, 16B chunks swizzled p = c ^ (r&3).
__global__ __launch_bounds__(512, 2) void gemm_fc_k(const float* __restrict__ A,
    const unsigned short* __restrict__ BT, float* __restrict__ Cacc, int ksteps) {
  __shared__ unsigned short Al[2][256 * 32];  // 2 x 16 KB
  __shared__ unsigned short Bl[2][256 * 32];  // 2 x 16 KB
  const int K = FEAT;
  int tid = threadIdx.x;
  int m0 = (blockIdx.x >> 1) * 256;
  int n0 = (blockIdx.x & 1) * 256;
  int kbase = blockIdx.y * ksteps * 32;
  int wid = tid >> 6, lane = tid & 63;
  int wm = wid >> 1, wn = wid & 1;            // 4 x 2 waves; wave = 64 rows x 128 cols
  int lrow = lane & 15, lko = lane >> 4;

  f32x4 acc[4][8];
  #pragma unroll
  for (int i = 0; i < 4; i++)
    #pragma unroll
    for (int j = 0; j < 8; j++) acc[i][j] = (f32x4){0.f, 0.f, 0.f, 0.f};

  float4 pa[4];   // one tile's A slice per thread (2 chunks x 8 fp32)

  auto loadA_regs = [&](int k0) {
    #pragma unroll
    for (int j = 0; j < 2; j++) {
      int ch = tid + j * 512;                 // 1024 chunks: r = ch>>2, c = ch&3
      int r = ch >> 2, c = ch & 3;
      const float* g = A + (size_t)(m0 + r) * K + k0 + c * 8;
      pa[2 * j]     = *reinterpret_cast<const float4*>(g);
      pa[2 * j + 1] = *reinterpret_cast<const float4*>(g + 4);
    }
  };
  auto cvtWriteA = [&](int buf) {
    #pragma unroll
    for (int j = 0; j < 2; j++) {
      int ch = tid + j * 512;
      int r = ch >> 2, c = ch & 3;
      int p = c ^ (r & 3);
      int4 o;
      o.x = (int)cvtpk(pa[2 * j].x,     pa[2 * j].y);
      o.y = (int)cvtpk(pa[2 * j].z,     pa[2 * j].w);
      o.z = (int)cvtpk(pa[2 * j + 1].x, pa[2 * j + 1].y);
      o.w = (int)cvtpk(pa[2 * j + 1].z, pa[2 * j + 1].w);
      *reinterpret_cast<int4*>((char*)Al[buf] + r * 64 + p * 16) = o;
    }
  };
  auto stageB = [&](int buf, int k0) {
    #pragma unroll
    for (int j = 0; j < 2; j++) {
      int chb = wid * 128 + j * 64;           // wave-uniform base chunk
      int ch = chb + lane;                    // physical chunk: r=ch>>2, p=ch&3
      int r = ch >> 2, c = (ch & 3) ^ (r & 3);
      load_lds16(BT + (size_t)(n0 + r) * K + k0 + c * 8, (char*)Bl[buf] + chb * 16);
    }
  };

  // ---- prologue: tiles 0 and 1 ----
  loadA_regs(kbase);
  stageB(0, kbase);
  cvtWriteA(0);                               // waits A0 regs (B0 stays in flight)
  loadA_regs(kbase + 32);
  stageB(1, kbase + 32);
  asm volatile("s_waitcnt vmcnt(6)" ::: "memory");   // B0 landed
  asm volatile("s_waitcnt lgkmcnt(0)" ::: "memory"); // Al[0] writes visible
  __builtin_amdgcn_s_barrier();
  __builtin_amdgcn_sched_barrier(0);

  int cur = 0;
  for (int t = 0; t < ksteps; ++t) {
    bool more1 = (t + 1 < ksteps), more2 = (t + 2 < ksteps);
    // A(t+1): pa -> Al[cur^1]
    if (more1) cvtWriteA(cur ^ 1);
    // frag reads for tile t
    short8 af[4], bf8[8];
    #pragma unroll
    for (int mi = 0; mi < 4; mi++) {
      int R = wm * 64 + mi * 16 + lrow;
      int p = lko ^ (R & 3);
      af[mi] = *reinterpret_cast<const short8*>((char*)Al[cur] + R * 64 + p * 16);
    }
    #pragma unroll
    for (int ni = 0; ni < 8; ni++) {
      int R = wn * 128 + ni * 16 + lrow;
      int p = lko ^ (R & 3);
      bf8[ni] = *reinterpret_cast<const short8*>((char*)Bl[cur] + R * 64 + p * 16);
    }
    // issue A regs for t+2 (in flight across the barrier)
    if (more2) loadA_regs(kbase + (t + 2) * 32);
    asm volatile("s_waitcnt lgkmcnt(0)" ::: "memory");  // frags in regs; A(t+1) writes visible
    __builtin_amdgcn_s_barrier();
    __builtin_amdgcn_sched_barrier(0);
    // stage B(t+2) into the buffer we just finished reading
    if (more2) stageB(cur, kbase + (t + 2) * 32);
    // compute tile t
    #pragma unroll
    for (int mi = 0; mi < 4; mi++)
      #pragma unroll
      for (int ni = 0; ni < 8; ni++)
        acc[mi][ni] = __builtin_amdgcn_mfma_f32_16x16x32_bf16(af[mi], bf8[ni], acc[mi][ni], 0, 0, 0);
    // counted wait: B(t+1) landed; A(t+2)/B(t+2) (6 ops) stay in flight
    if (more1) {
      if (more2) { asm volatile("s_waitcnt vmcnt(6)" ::: "memory"); }
      else       { asm volatile("s_waitcnt vmcnt(0)" ::: "memory"); }
      __builtin_amdgcn_sched_barrier(0);
    }
    cur ^= 1;
  }

  #pragma unroll
  for (int mi = 0; mi < 4; mi++)
    #pragma unroll
    for (int ni = 0; ni < 8; ni++)
      #pragma unroll
      for (int r = 0; r < 4; r++) {
        int row = m0 + wm * 64 + mi * 16 + lko * 4 + r;   // C/D: row=(lane>>4)*4+r
        int col = n0 + wn * 128 + ni * 16 + lrow;         //      col=lane&15
        atomicAdd(&Cacc[(size_t)row * DFC + col], acc[mi][ni][r]);
      }
}

// ---------- layer MFMA GEMM (bf16 A): 128x128 tile, BK=64, dbuf ----------
__global__ __launch_bounds__(256) void gemm_l_k(const unsigned short* __restrict__ A,
    const unsigned short* __restrict__ BT, float* __restrict__ Cacc,
    int K, int Ncols, int tiles_n, int ksteps) {
  __shared__ unsigned short Al[2][128 * 64];
  __shared__ unsigned short Bl[2][128 * 64];
  int tid = threadIdx.x;
  int m0 = (blockIdx.x / tiles_n) * 128;
  int n0 = (blockIdx.x % tiles_n) * 128;
  int kbase = blockIdx.y * ksteps * 64;
  int wid = tid >> 6, lane = tid & 63;
  int wm = wid >> 1, wn = wid & 1;
  int lrow = lane & 15, lko = lane >> 4;

  f32x4 acc[4][4];
  #pragma unroll
  for (int i = 0; i < 4; i++)
    #pragma unroll
    for (int j = 0; j < 4; j++) acc[i][j] = (f32x4){0.f, 0.f, 0.f, 0.f};

  auto stage = [&](unsigned short (*L)[128 * 64], const unsigned short* G, int buf, int k0) {
    #pragma unroll
    for (int j = 0; j < 4; j++) {
      int chb = j * 256 + wid * 64;
      int ch = chb + lane;
      int r = ch >> 3, c = (ch & 7) ^ (r & 7);
      load_lds16(G + (size_t)r * K + k0 + c * 8, (char*)L[buf] + chb * 16);
    }
  };

  stage(Al, A + (size_t)m0 * K, 0, kbase);
  stage(Bl, BT + (size_t)n0 * K, 0, kbase);
  __syncthreads();

  int cur = 0;
  for (int t = 0; t < ksteps; ++t) {
    bool more = (t + 1 < ksteps);
    if (more) {
      stage(Al, A + (size_t)m0 * K, cur ^ 1, kbase + (t + 1) * 64);
      stage(Bl, BT + (size_t)n0 * K, cur ^ 1, kbase + (t + 1) * 64);
    }
    #pragma unroll
    for (int kk = 0; kk < 2; kk++) {
      short8 af[4], bfv[4];
      #pragma unroll
      for (int mi = 0; mi < 4; mi++) {
        int R = wm * 64 + mi * 16 + lrow;
        int slot = ((kk << 2) | lko) ^ (lrow & 7);
        af[mi] = *reinterpret_cast<const short8*>((char*)Al[cur] + R * 128 + slot * 16);
      }
      #pragma unroll
      for (int ni = 0; ni < 4; ni++) {
        int R = wn * 64 + ni * 16 + lrow;
        int slot = ((kk << 2) | lko) ^ (lrow & 7);
        bfv[ni] = *reinterpret_cast<const short8*>((char*)Bl[cur] + R * 128 + slot * 16);
      }
      #pragma unroll
      for (int mi = 0; mi < 4; mi++)
        #pragma unroll
        for (int ni = 0; ni < 4; ni++)
          acc[mi][ni] = __builtin_amdgcn_mfma_f32_16x16x32_bf16(af[mi], bfv[ni], acc[mi][ni], 0, 0, 0);
    }
    __syncthreads();
    cur ^= 1;
  }
  #pragma unroll
  for (int mi = 0; mi < 4; mi++)
    #pragma unroll
    for (int ni = 0; ni < 4; ni++)
      #pragma unroll
      for (int r = 0; r < 4; r++) {
        int row = m0 + wm * 64 + mi * 16 + lko * 4 + r;
        int col = n0 + wn * 64 + ni * 16 + lrow;
        atomicAdd(&Cacc[(size_t)row * Ncols + col], acc[mi][ni][r]);
      }
}

// ---------- feats finalize: +bias -> fp32 out + bf16 copy ----------
__global__ void feats_fin_k(const float* __restrict__ facc, const float* __restrict__ bfc,
                            float* __restrict__ outf, unsigned short* __restrict__ outbf) {
  int i = blockIdx.y;
  int n = blockIdx.x * 256 + threadIdx.x;
  float v = facc[(size_t)i * DFC + n] + bfc[n];
  outf[(size_t)i * DFC + n] = v;
  outbf[(size_t)i * DFC + n] = bfbits(v);
}

// ---------- exact label path ----------
__global__ void seg_sum_part_k(const float* __restrict__ x, const int* __restrict__ slab,
                               float* __restrict__ sxp) {
  int k4 = blockIdx.x * 256 + threadIdx.x;
  if (k4 >= FEAT / 4) return;
  int k = k4 * 4;
  int i0 = blockIdx.y * 64, i1 = i0 + 64;
  float4 a0 = {0,0,0,0}, a1 = {0,0,0,0}, a2 = {0,0,0,0}, a3 = {0,0,0,0};
  #pragma unroll 4
  for (int i = i0; i < i1; i++) {
    float4 v = *reinterpret_cast<const float4*>(x + (size_t)i * FEAT + k);
    int c = slab[i];
    float m0 = (c == 0) ? 1.f : 0.f, m1 = (c == 1) ? 1.f : 0.f;
    float m2 = (c == 2) ? 1.f : 0.f, m3 = (c == 3) ? 1.f : 0.f;
    a0.x += m0 * v.x; a0.y += m0 * v.y; a0.z += m0 * v.z; a0.w += m0 * v.w;
    a1.x += m1 * v.x; a1.y += m1 * v.y; a1.z += m1 * v.z; a1.w += m1 * v.w;
    a2.x += m2 * v.x; a2.y += m2 * v.y; a2.z += m2 * v.z; a2.w += m2 * v.w;
    a3.x += m3 * v.x; a3.y += m3 * v.y; a3.z += m3 * v.z; a3.w += m3 * v.w;
  }
  size_t base = (size_t)blockIdx.y * 4 * FEAT;
  *reinterpret_cast<float4*>(sxp + base + 0 * FEAT + k) = a0;
  *reinterpret_cast<float4*>(sxp + base + 1 * FEAT + k) = a1;
  *reinterpret_cast<float4*>(sxp + base + 2 * FEAT + k) = a2;
  *reinterpret_cast<float4*>(sxp + base + 3 * FEAT + k) = a3;
}

__global__ void seg_sum_reduce_k(const float* __restrict__ sxp, float* __restrict__ sx) {
  int k4 = blockIdx.x * 256 + threadIdx.x;
  if (k4 >= FEAT / 4) return;
  int k = k4 * 4;
  int c = blockIdx.y;
  double s0 = 0, s1 = 0, s2 = 0, s3 = 0;
  #pragma unroll
  for (int p = 0; p < 16; p++) {
    float4 v = *reinterpret_cast<const float4*>(sxp + ((size_t)p * 4 + c) * FEAT + k);
    s0 += (double)v.x; s1 += (double)v.y; s2 += (double)v.z; s3 += (double)v.w;
  }
  float4 r; r.x = (float)s0; r.y = (float)s1; r.z = (float)s2; r.w = (float)s3;
  *reinterpret_cast<float4*>(sx + (size_t)c * FEAT + k) = r;
}

__global__ void count_src_k(const int* __restrict__ slab, int* __restrict__ cnt) {
  __shared__ int c[4];
  if (threadIdx.x < 4) c[threadIdx.x] = 0;
  __syncthreads();
  for (int i = threadIdx.x; i < SLEN; i += 256) atomicAdd(&c[slab[i]], 1);
  __syncthreads();
  if (threadIdx.x < 4) cnt[threadIdx.x] = c[threadIdx.x];
}

__global__ void centers_part_k(const float* __restrict__ sx, const float* __restrict__ W,
                               double* __restrict__ cpart) {
  int n = blockIdx.x * 64 + (threadIdx.x & 63);
  int cc = threadIdx.x >> 6;
  int kb = blockIdx.y * (FEAT / CSPLIT), ke = kb + FEAT / CSPLIT;
  const float* sr = sx + (size_t)cc * FEAT;
  double acc = 0.0;
  #pragma unroll 4
  for (int k = kb; k < ke; k++)
    acc += (double)sr[k] * (double)W[(size_t)k * DFC + n];
  cpart[((size_t)blockIdx.y * 4 + cc) * DFC + n] = acc;
}

__global__ void centers_reduce_k(const double* __restrict__ cpart, const float* __restrict__ bfc,
                                 const int* __restrict__ cntsrc, float* __restrict__ Cent) {
  int idx = blockIdx.x * 256 + threadIdx.x;
  int cc = idx >> 9, n = idx & 511;
  double s = 0.0;
  #pragma unroll 4
  for (int p = 0; p < CSPLIT; p++) s += cpart[((size_t)p * 4 + cc) * DFC + n];
  Cent[idx] = (float)(s + (double)cntsrc[cc] * (double)bfc[n]);
}

__global__ void wc_k(const float* __restrict__ W, const float* __restrict__ Cent,
                     float* __restrict__ wc) {
  __shared__ float cs[4 * DFC];
  for (int i = threadIdx.x; i < 4 * DFC; i += 256) cs[i] = Cent[i];
  __syncthreads();
  int k = blockIdx.x * 256 + threadIdx.x;
  if (k >= FEAT) return;
  const float* wr = W + (size_t)k * DFC;
  double a0 = 0, a1 = 0, a2 = 0, a3 = 0;
  #pragma unroll 2
  for (int n = 0; n < DFC; n += 4) {
    float4 w4 = *reinterpret_cast<const float4*>(wr + n);
    a0 += (double)w4.x * cs[0 * DFC + n] + (double)w4.y * cs[0 * DFC + n + 1]
        + (double)w4.z * cs[0 * DFC + n + 2] + (double)w4.w * cs[0 * DFC + n + 3];
    a1 += (double)w4.x * cs[1 * DFC + n] + (double)w4.y * cs[1 * DFC + n + 1]
        + (double)w4.z * cs[1 * DFC + n + 2] + (double)w4.w * cs[1 * DFC + n + 3];
    a2 += (double)w4.x * cs[2 * DFC + n] + (double)w4.y * cs[2 * DFC + n + 1]
        + (double)w4.z * cs[2 * DFC + n + 2] + (double)w4.w * cs[2 * DFC + n + 3];
    a3 += (double)w4.x * cs[3 * DFC + n] + (double)w4.y * cs[3 * DFC + n + 1]
        + (double)w4.z * cs[3 * DFC + n + 2] + (double)w4.w * cs[3 * DFC + n + 3];
  }
  float4 r; r.x = (float)a0; r.y = (float)a1; r.z = (float)a2; r.w = (float)a3;
  *reinterpret_cast<float4*>(wc + 4 * (size_t)k) = r;
}

__global__ void kj_k(const float* __restrict__ Cent, const float* __restrict__ bfc,
                     float* __restrict__ Kj) {
  int j = threadIdx.x >> 6, lane = threadIdx.x & 63;
  float cn = 0.f, bc = 0.f;
  for (int n = lane; n < DFC; n += 64) {
    float c = Cent[j * DFC + n];
    cn += c * c; bc += bfc[n] * c;
  }
  #pragma unroll
  for (int m = 32; m >= 1; m >>= 1) { cn += __shfl_xor(cn, m); bc += __shfl_xor(bc, m); }
  if (lane == 0) Kj[j] = cn - 2.f * bc;
}

__global__ void d2_labels_k(const float* __restrict__ x, const float* __restrict__ wc,
                            const float* __restrict__ Kj, int* __restrict__ tlab) {
  int row = blockIdx.x;
  int tid = threadIdx.x;
  const float* xr = x + (size_t)(SLEN + row) * FEAT;
  double a0 = 0, a1 = 0, a2 = 0, a3 = 0;
  #pragma unroll 2
  for (int k = tid; k < FEAT; k += 256) {
    float xv = xr[k];
    float4 w4 = *reinterpret_cast<const float4*>(wc + 4 * (size_t)k);
    a0 += (double)xv * w4.x; a1 += (double)xv * w4.y;
    a2 += (double)xv * w4.z; a3 += (double)xv * w4.w;
  }
  #pragma unroll
  for (int m = 32; m >= 1; m >>= 1) {
    a0 += __shfl_xor(a0, m); a1 += __shfl_xor(a1, m);
    a2 += __shfl_xor(a2, m); a3 += __shfl_xor(a3, m);
  }
  __shared__ double s[4][4];
  int wid = tid >> 6, lane = tid & 63;
  if (lane == 0) { s[wid][0] = a0; s[wid][1] = a1; s[wid][2] = a2; s[wid][3] = a3; }
  __syncthreads();
  if (tid == 0) {
    double t0 = s[0][0] + s[1][0] + s[2][0] + s[3][0];
    double t1 = s[0][1] + s[1][1] + s[2][1] + s[3][1];
    double t2 = s[0][2] + s[1][2] + s[2][2] + s[3][2];
    double t3 = s[0][3] + s[1][3] + s[2][3] + s[3][3];
    double s0 = (double)Kj[0] - 2.0 * t0;
    double s1 = (double)Kj[1] - 2.0 * t1;
    double s2 = (double)Kj[2] - 2.0 * t2;
    double s3 = (double)Kj[3] - 2.0 * t3;
    int bi = 0; double b = s0;
    if (s1 < b) { b = s1; bi = 1; }
    if (s2 < b) { b = s2; bi = 2; }
    if (s3 < b) { b = s3; bi = 3; }
    tlab[row] = bi;
  }
}

__global__ void finalize_labels_k(const int* __restrict__ slab, const int* __restrict__ tlab,
                                  const int* __restrict__ cntsrc, int* __restrict__ alllab,
                                  float* __restrict__ dinv) {
  __shared__ int ct[4];
  if (threadIdx.x < 4) ct[threadIdx.x] = 0;
  __syncthreads();
  for (int i = threadIdx.x; i < SLEN; i += 256) atomicAdd(&ct[tlab[i]], 1);
  __syncthreads();
  for (int i = threadIdx.x; i < NROWS; i += 256) {
    int lab = (i < SLEN) ? slab[i] : tlab[i - SLEN];
    alllab[i] = lab;
    float rs = (i < SLEN) ? (2.f + (float)ct[lab])
                          : (1.f + (float)cntsrc[lab] + (float)ct[lab]);
    dinv[i] = 1.f / sqrtf(rs);
  }
}

// ---------- A_norm dense write (float4) ----------
__global__ void anorm_k(const int* __restrict__ alllab, const float* __restrict__ dinv,
                        float* __restrict__ Aout) {
  int i = blockIdx.y;
  int j0 = (blockIdx.x * 256 + threadIdx.x) * 4;
  int li = alllab[i];
  float di = dinv[i];
  int4 lj = *reinterpret_cast<const int4*>(alllab + j0);
  float4 dj = *reinterpret_cast<const float4*>(dinv + j0);
  int jj[4] = {lj.x, lj.y, lj.z, lj.w};
  float dd[4] = {dj.x, dj.y, dj.z, dj.w};
  float4 o;
  float* op = &o.x;
  #pragma unroll
  for (int e = 0; e < 4; e++) {
    int j = j0 + e;
    float v;
    if (i == j) v = 2.f * di * dd[e];
    else if (i < SLEN && j < SLEN) v = 0.f;
    else v = (li == jj[e]) ? di * dd[e] : 0.f;
    op[e] = v;
  }
  *reinterpret_cast<float4*>(Aout + (size_t)i * NROWS + j0) = o;
}

// ---------- propagation ----------
__global__ void reduce_st_k(const float* __restrict__ Xacc, const int* __restrict__ alllab,
                            const float* __restrict__ dinv, float* __restrict__ ST, int D) {
  int n = blockIdx.x * 256 + threadIdx.x;
  int i0 = blockIdx.y * 32, i1 = i0 + 32;
  float s[4] = {0, 0, 0, 0}, tt[4] = {0, 0, 0, 0};
  for (int i = i0; i < i1; ++i) {
    float v = dinv[i] * Xacc[(size_t)i * D + n];
    int lab = alllab[i];
    bool src = i < SLEN;
    #pragma unroll
    for (int c = 0; c < 4; c++) {
      s[c]  += (src && lab == c) ? v : 0.f;
      tt[c] += (!src && lab == c) ? v : 0.f;
    }
  }
  #pragma unroll
  for (int c = 0; c < 4; c++) {
    atomicAdd(&ST[c * D + n], s[c]);
    atomicAdd(&ST[(4 + c) * D + n], tt[c]);
  }
}

__global__ void apply_prop_k(const float* __restrict__ Xacc, const float* __restrict__ ST,
                             const int* __restrict__ alllab, const float* __restrict__ dinv,
                             const float* __restrict__ bias, float* __restrict__ outf,
                             unsigned short* __restrict__ outbf, int D) {
  int i = blockIdx.y;
  int n = blockIdx.x * 256 + threadIdx.x;
  float dv = dinv[i];
  int lab = alllab[i];
  float xv = Xacc[(size_t)i * D + n];
  float z;
  if (i < SLEN) z = dv * (2.f * dv * xv + ST[(4 + lab) * D + n]);
  else          z = dv * (ST[lab * D + n] + ST[(4 + lab) * D + n] + dv * xv);
  z += bias[n];
  z = fmaxf(z, 0.f);
  if (outf)  outf[(size_t)i * D + n] = z;
  if (outbf) outbf[(size_t)i * D + n] = bfbits(z);
}

extern "C" void kernel_launch(void* const* d_in, const int* in_sizes, int n_in,
                              void* d_out, int out_size, void* d_ws, size_t ws_size,
                              hipStream_t stream) {
  const float* x    = (const float*)d_in[0];
  const float* Wfc  = (const float*)d_in[1];
  const float* bfc  = (const float*)d_in[2];
  const float* Wg1  = (const float*)d_in[3];
  const float* bg1  = (const float*)d_in[4];
  const float* Wg2  = (const float*)d_in[5];
  const float* bg2  = (const float*)d_in[6];
  const int*   slab = (const int*)d_in[7];

  float* out = (float*)d_out;
  float* out_h = out;                       // 2048*256
  float* out_A = out + 524288;              // 2048*2048
  float* out_f = out + 4718592;             // 2048*512

  char* w = (char*)d_ws;
  unsigned short* wT   = (unsigned short*)(w);
  unsigned short* g1T  = (unsigned short*)(w + 25690112);
  unsigned short* g2T  = (unsigned short*)(w + 26214400);
  float* facc          = (float*)(w + 26476544);
  unsigned short* fbf  = (unsigned short*)(w + 30670848);
  float* x1acc         = (float*)(w + 32768000);
  unsigned short* h1bf = (unsigned short*)(w + 36962304);
  float* x2acc         = (float*)(w + 39059456);
  float* sx            = (float*)(w + 41156608);
  float* Cent          = (float*)(w + 41623552);
  float* wc            = (float*)(w + 41631744);
  float* Kj            = (float*)(w + 42033152);
  int*   tlab          = (int*)(w + 42033216);
  int*   alllab        = (int*)(w + 42037312);
  float* dinv          = (float*)(w + 42045504);
  int*   cntsrc        = (int*)(w + 42053696);
  float* ST1           = (float*)(w + 42053760);
  float* ST2           = (float*)(w + 42070144);

  // aliased scratch (regions dead during the label phase)
  float*  sxp     = (float*)(w + 32768000);   // alias x1acc (+h1bf head), 6.42 MB
  double* cpart_d = (double*)(w + 39059456);  // alias x2acc, 2 MB

  hipMemsetAsync(facc,  0, (size_t)NROWS * DFC * 4, stream);
  hipMemsetAsync(ST1,   0, 8 * DG1 * 4, stream);
  hipMemsetAsync(ST2,   0, 8 * DG2 * 4, stream);

  // weight transposes + bf16 convert
  transpose_cvt_k<<<dim3(FEAT / 64, DFC / 64), 256, 0, stream>>>(Wfc, wT, FEAT, DFC);
  transpose_cvt_k<<<dim3(DFC / 64, DG1 / 64), 256, 0, stream>>>(Wg1, g1T, DFC, DG1);
  transpose_cvt_k<<<dim3(DG1 / 64, DG2 / 64), 256, 0, stream>>>(Wg2, g2T, DG1, DG2);

  // FC GEMM: 256x256 tile, BK=32, split-K 16 (784/16 = 49 steps) -> 256 blocks
  gemm_fc_k<<<dim3(16, 16), 512, 0, stream>>>(x, wT, facc, 49);
  feats_fin_k<<<dim3(DFC / 256, NROWS), 256, 0, stream>>>(facc, bfc, out_f, fbf);

  // exact label path
  seg_sum_part_k<<<dim3(25, 16), 256, 0, stream>>>(x, slab, sxp);
  seg_sum_reduce_k<<<dim3(25, 4), 256, 0, stream>>>(sxp, sx);
  count_src_k<<<1, 256, 0, stream>>>(slab, cntsrc);
  centers_part_k<<<dim3(DFC / 64, CSPLIT), 256, 0, stream>>>(sx, Wfc, cpart_d);
  centers_reduce_k<<<dim3(4 * DFC / 256), 256, 0, stream>>>(cpart_d, bfc, cntsrc, Cent);
  wc_k<<<dim3(FEAT / 256), 256, 0, stream>>>(Wfc, Cent, wc);
  kj_k<<<1, 256, 0, stream>>>(Cent, bfc, Kj);
  d2_labels_k<<<dim3(NROWS - SLEN), 256, 0, stream>>>(x, wc, Kj, tlab);
  finalize_labels_k<<<1, 256, 0, stream>>>(slab, tlab, cntsrc, alllab, dinv);

  // A_norm dense output
  anorm_k<<<dim3(NROWS / 1024, NROWS), 256, 0, stream>>>(alllab, dinv, out_A);

  // GCN layer 1
  hipMemsetAsync(x1acc, 0, (size_t)NROWS * DG1 * 4, stream);
  gemm_l_k<<<dim3(16 * 4, 4), 256, 0, stream>>>(fbf, g1T, x1acc, DFC, DG1, 4, 2);
  reduce_st_k<<<dim3(DG1 / 256, 64), 256, 0, stream>>>(x1acc, alllab, dinv, ST1, DG1);
  apply_prop_k<<<dim3(DG1 / 256, NROWS), 256, 0, stream>>>(x1acc, ST1, alllab, dinv, bg1,
                                                           nullptr, h1bf, DG1);

  // GCN layer 2
  hipMemsetAsync(x2acc, 0, (size_t)NROWS * DG2 * 4, stream);
  gemm_l_k<<<dim3(16 * 2, 8), 256, 0, stream>>>(h1bf, g2T, x2acc, DG1, DG2, 2, 1);
  reduce_st_k<<<dim3(DG2 / 256, 64), 256, 0, stream>>>(x2acc, alllab, dinv, ST2, DG2);
  apply_prop_k<<<dim3(DG2 / 256, NROWS), 256, 0, stream>>>(x2acc, ST2, alllab, dinv, bg2,
                                                           out_h, nullptr, DG2);

  (void)in_sizes; (void)n_in; (void)out_size; (void)ws_size;
}